// Round 1
// baseline (1523.282 us; speedup 1.0000x reference)
//
#include <hip/hip_runtime.h>
#include <cstddef>
#include <cstdint>

// ---------------- problem constants ----------------
#define C_DIM   1536
#define L_SEQ   2400
#define L_CTX   512
#define N_HEADS 12
#define D_HEAD  128
#define FF_DIM  8960
#define F_GRID  2
#define H_GRID  30
#define W_GRID  40
#define EPS_F   1e-6f

#define ROPE_P0 22
#define ROPE_P1 43   // p0 + p1

typedef __attribute__((ext_vector_type(8))) short short8;   // 8 bf16 = 4 VGPRs
typedef __attribute__((ext_vector_type(4))) float f32x4;

__device__ inline unsigned short f2bf(float f) {
    union { float f; unsigned int u; } v; v.f = f;
    unsigned int r = v.u + 0x7FFF + ((v.u >> 16) & 1);
    return (unsigned short)(r >> 16);
}

#define GL2LDS(gp, lp) \
    __builtin_amdgcn_global_load_lds((const __attribute__((address_space(1))) void*)(gp), \
                                     (__attribute__((address_space(3))) void*)(lp), 16, 0, 0)

// ---------------- small elementwise kernels ----------------

__global__ __launch_bounds__(256) void k_embed(const float* __restrict__ mod,
                                               const float* __restrict__ e,
                                               float* __restrict__ ev, int n) {
    int i = blockIdx.x * 256 + threadIdx.x;
    if (i < n) ev[i] = mod[i] + e[i];
}

// concat up to 3 bias vectors of length ne into dst
__global__ __launch_bounds__(256) void k_catbias(float* __restrict__ dst,
                                                 const float* __restrict__ b0,
                                                 const float* __restrict__ b1,
                                                 const float* __restrict__ b2,
                                                 int ne, int n) {
    int i = blockIdx.x * 256 + threadIdx.x;
    if (i >= n) return;
    const float* s = (i < ne) ? b0 : (i < 2 * ne) ? b1 : b2;
    dst[i] = s[i % ne];
}

// C[r][c] = bias[c]  (pre-init for split-K atomic accumulation)
__global__ __launch_bounds__(256) void k_initbias(float* __restrict__ C,
                                                  const float* __restrict__ bias,
                                                  int n, int N) {
    int i4 = (blockIdx.x * 256 + threadIdx.x) * 4;
    if (i4 >= n) return;
    int col = i4 % N;
    *(float4*)(C + i4) = *(const float4*)(bias + col);
}

// out = a + b * scale(ev row ei); optional bf16 secondary output. 2 elems/thread.
__global__ __launch_bounds__(256) void k_resid2(const float* __restrict__ a,
                                                const float* __restrict__ b,
                                                const float* __restrict__ ev, int ei,
                                                float* __restrict__ out,
                                                unsigned short* __restrict__ outb, int n) {
    int i = (blockIdx.x * 256 + threadIdx.x) * 2;
    if (i >= n) return;
    int c = i % C_DIM;
    float s0 = 1.f, s1 = 1.f;
    if (ei >= 0) {
        s0 = ev[ei * C_DIM + c];
        s1 = ev[ei * C_DIM + c + 1];
    }
    float2 av = *(const float2*)(a + i);
    float2 bv = *(const float2*)(b + i);
    float o0 = av.x + bv.x * s0;
    float o1 = av.y + bv.y * s1;
    *(float2*)(out + i) = make_float2(o0, o1);
    if (outb) {
        unsigned int pk = (unsigned int)f2bf(o0) | ((unsigned int)f2bf(o1) << 16);
        *(unsigned int*)(outb + i) = pk;
    }
}

// fp32 -> bf16 convert
__global__ __launch_bounds__(256) void k_tobf(const float* __restrict__ X,
                                              unsigned short* __restrict__ Y, int n) {
    int i = (blockIdx.x * 256 + threadIdx.x) * 2;
    if (i >= n) return;
    float2 v = *(const float2*)(X + i);
    unsigned int pk = (unsigned int)f2bf(v.x) | ((unsigned int)f2bf(v.y) << 16);
    *(unsigned int*)(Y + i) = pk;
}

// ---------------- LayerNorm + modulation -> bf16 ----------------
__global__ __launch_bounds__(256) void k_lnmod_bf16(const float* __restrict__ X,
                                                    const float* __restrict__ ev,
                                                    int i0, int i1,
                                                    unsigned short* __restrict__ H) {
    __shared__ float rs[256];
    __shared__ float rs2[256];
    int row = blockIdx.x, tid = threadIdx.x;
    const float* xr = X + (size_t)row * C_DIM;
    float2 vals[3];
    float s = 0.f, s2 = 0.f;
#pragma unroll
    for (int i = 0; i < 3; ++i) {
        float2 v = *(const float2*)(xr + 2 * (tid + 256 * i));
        vals[i] = v;
        s += v.x + v.y; s2 += v.x * v.x + v.y * v.y;
    }
    rs[tid] = s; rs2[tid] = s2;
    __syncthreads();
    for (int st = 128; st > 0; st >>= 1) {
        if (tid < st) { rs[tid] += rs[tid + st]; rs2[tid] += rs2[tid + st]; }
        __syncthreads();
    }
    float mean = rs[0] * (1.0f / C_DIM);
    float var  = rs2[0] * (1.0f / C_DIM) - mean * mean;
    float rinv = rsqrtf(var + EPS_F);
    const float* E0 = ev + (size_t)i0 * C_DIM;
    const float* E1 = ev + (size_t)i1 * C_DIM;
    unsigned short* hr = H + (size_t)row * C_DIM;
#pragma unroll
    for (int i = 0; i < 3; ++i) {
        int c = 2 * (tid + 256 * i);
        float o0 = E0[c]     + (vals[i].x - mean) * rinv * (1.0f + E1[c]);
        float o1 = E0[c + 1] + (vals[i].y - mean) * rinv * (1.0f + E1[c + 1]);
        unsigned int pk = (unsigned int)f2bf(o0) | ((unsigned int)f2bf(o1) << 16);
        *(unsigned int*)(hr + c) = pk;
    }
}

// ---------------- RMSNorm + optional RoPE -> bf16 (strided input) ----------------
__global__ __launch_bounds__(256) void k_rms_rope_bf16(const float* __restrict__ X,
                                                       const float* __restrict__ w,
                                                       const float* __restrict__ freqs,
                                                       int do_rope, float outscale,
                                                       unsigned short* __restrict__ Y,
                                                       int ldx) {
    __shared__ float rs[256];
    int row = blockIdx.x, tid = threadIdx.x;
    const float* xr = X + (size_t)row * ldx;
    float2 vals[3];
    float ss = 0.f;
#pragma unroll
    for (int i = 0; i < 3; ++i) {
        int p = tid + 256 * i;
        float2 v = *(const float2*)(xr + 2 * p);
        vals[i] = v;
        ss += v.x * v.x + v.y * v.y;
    }
    rs[tid] = ss;
    __syncthreads();
    for (int st = 128; st > 0; st >>= 1) {
        if (tid < st) rs[tid] += rs[tid + st];
        __syncthreads();
    }
    float rinv = rsqrtf(rs[0] * (1.0f / C_DIM) + EPS_F);
    int f = row / (H_GRID * W_GRID);
    int rem = row % (H_GRID * W_GRID);
    int hh = rem / W_GRID, ww = rem % W_GRID;
    unsigned short* yr = Y + (size_t)row * C_DIM;
#pragma unroll
    for (int i = 0; i < 3; ++i) {
        int p = tid + 256 * i;
        int c = 2 * p;
        float a = vals[i].x * rinv * w[c];
        float b = vals[i].y * rinv * w[c + 1];
        if (do_rope) {
            int j = p & 63;
            int idx = (j < ROPE_P0) ? f : (j < ROPE_P1) ? hh : ww;
            float cv = freqs[(idx * 64 + j) * 2 + 0];
            float sv = freqs[(idx * 64 + j) * 2 + 1];
            float na = a * cv - b * sv;
            float nb = a * sv + b * cv;
            a = na; b = nb;
        }
        a *= outscale; b *= outscale;
        unsigned int pk = (unsigned int)f2bf(a) | ((unsigned int)f2bf(b) << 16);
        *(unsigned int*)(yr + c) = pk;
    }
}

// ---------------- weight transpose: fp32 [K][N] -> bf16 [N][K] ----------------
__global__ __launch_bounds__(256) void k_wt(const float* __restrict__ W,
                                            unsigned short* __restrict__ WT,
                                            int K, int N) {
    __shared__ float tile[32][33];
    int k0 = blockIdx.x * 32, n0 = blockIdx.y * 32;
    int t = threadIdx.x;
    int r = t >> 3, c4 = (t & 7) * 4;
    float4 v = *(const float4*)(W + (size_t)(k0 + r) * N + n0 + c4);
    tile[r][c4 + 0] = v.x; tile[r][c4 + 1] = v.y;
    tile[r][c4 + 2] = v.z; tile[r][c4 + 3] = v.w;
    __syncthreads();
    int n = t >> 3, k4 = (t & 7) * 4;
    uint2 o;
    o.x = (unsigned int)f2bf(tile[k4 + 0][n]) | ((unsigned int)f2bf(tile[k4 + 1][n]) << 16);
    o.y = (unsigned int)f2bf(tile[k4 + 2][n]) | ((unsigned int)f2bf(tile[k4 + 3][n]) << 16);
    *(uint2*)(WT + (size_t)(n0 + n) * K + k0 + k4) = o;
}

// ---------------- V transpose: fp32 [Lk][ldv] -> bf16 [12][128][Lk] ----------------
__global__ __launch_bounds__(256) void k_vt(const float* __restrict__ V,
                                            unsigned short* __restrict__ Vt, int Lk, int ldv) {
    __shared__ float tile[32][33];
    int k0 = blockIdx.x * 32, h = blockIdx.y, d0 = blockIdx.z * 32;
    int t = threadIdx.x;
    int k = t >> 3, d4 = (t & 7) * 4;
    float4 v = *(const float4*)(V + (size_t)(k0 + k) * ldv + h * D_HEAD + d0 + d4);
    tile[k][d4 + 0] = v.x; tile[k][d4 + 1] = v.y;
    tile[k][d4 + 2] = v.z; tile[k][d4 + 3] = v.w;
    __syncthreads();
    int d = t >> 3, k4 = (t & 7) * 4;
    uint2 o;
    o.x = (unsigned int)f2bf(tile[k4 + 0][d]) | ((unsigned int)f2bf(tile[k4 + 1][d]) << 16);
    o.y = (unsigned int)f2bf(tile[k4 + 2][d]) | ((unsigned int)f2bf(tile[k4 + 3][d]) << 16);
    *(uint2*)(Vt + (size_t)(h * D_HEAD + d0 + d) * Lk + k0 + k4) = o;
}

// ---------------- MFMA flash attention (bf16 in, bf16 out) ----------------
__global__ __launch_bounds__(256) void k_attn_mfma(const unsigned short* __restrict__ Qb,
                                                   const unsigned short* __restrict__ Kb,
                                                   const unsigned short* __restrict__ Vt,
                                                   unsigned short* __restrict__ O,
                                                   int Lq, int Lk) {
    __shared__ __align__(16) unsigned short Ks[32][136];
    __shared__ __align__(16) unsigned short Vs[128][40];
    __shared__ __align__(16) unsigned short Ps[4][16][40];
    const int tid = threadIdx.x;
    const int w = tid >> 6, lane = tid & 63;
    const int ln = lane & 15, lq = lane >> 4;
    const int h = blockIdx.y;
    const int q0 = blockIdx.x * 64 + w * 16;
    int qrow = q0 + ln; if (qrow >= Lq) qrow = Lq - 1;
    short8 qf[4];
#pragma unroll
    for (int c = 0; c < 4; ++c)
        qf[c] = *(const short8*)(Qb + (size_t)qrow * C_DIM + h * D_HEAD + c * 32 + lq * 8);
    f32x4 oacc[8];
#pragma unroll
    for (int t = 0; t < 8; ++t) oacc[t] = (f32x4){0.f, 0.f, 0.f, 0.f};
    float m_run[4] = {-3e38f, -3e38f, -3e38f, -3e38f};
    float l_run[4] = {0.f, 0.f, 0.f, 0.f};
    const float LOG2E = 1.4426950408889634f;

    for (int kb = 0; kb < Lk; kb += 32) {
        __syncthreads();
#pragma unroll
        for (int i = 0; i < 2; ++i) {
            int id = tid + i * 256;
            int r = id >> 4, c = id & 15;
            *(uint4*)&Ks[r][c * 8] =
                *(const uint4*)(Kb + (size_t)(kb + r) * C_DIM + h * D_HEAD + c * 8);
            int d = id >> 2, c2 = id & 3;
            *(uint4*)&Vs[d][c2 * 8] =
                *(const uint4*)(Vt + (size_t)(h * D_HEAD + d) * Lk + kb + c2 * 8);
        }
        __syncthreads();
        f32x4 c0 = (f32x4){0.f, 0.f, 0.f, 0.f};
        f32x4 c1 = (f32x4){0.f, 0.f, 0.f, 0.f};
#pragma unroll
        for (int c = 0; c < 4; ++c) {
            short8 b0 = *(const short8*)&Ks[ln][c * 32 + lq * 8];
            short8 b1 = *(const short8*)&Ks[16 + ln][c * 32 + lq * 8];
            c0 = __builtin_amdgcn_mfma_f32_16x16x32_bf16(qf[c], b0, c0, 0, 0, 0);
            c1 = __builtin_amdgcn_mfma_f32_16x16x32_bf16(qf[c], b1, c1, 0, 0, 0);
        }
        float alpha[4];
#pragma unroll
        for (int r = 0; r < 4; ++r) {
            float mx = fmaxf(c0[r], c1[r]);
            mx = fmaxf(mx, __shfl_xor(mx, 1));
            mx = fmaxf(mx, __shfl_xor(mx, 2));
            mx = fmaxf(mx, __shfl_xor(mx, 4));
            mx = fmaxf(mx, __shfl_xor(mx, 8));
            float mn = fmaxf(m_run[r], mx);
            alpha[r] = exp2f((m_run[r] - mn) * LOG2E);
            float p0 = exp2f((c0[r] - mn) * LOG2E);
            float p1 = exp2f((c1[r] - mn) * LOG2E);
            float s = p0 + p1;
            s += __shfl_xor(s, 1);
            s += __shfl_xor(s, 2);
            s += __shfl_xor(s, 4);
            s += __shfl_xor(s, 8);
            l_run[r] = l_run[r] * alpha[r] + s;
            m_run[r] = mn;
            Ps[w][lq * 4 + r][ln] = f2bf(p0);
            Ps[w][lq * 4 + r][16 + ln] = f2bf(p1);
        }
#pragma unroll
        for (int t = 0; t < 8; ++t)
#pragma unroll
            for (int r = 0; r < 4; ++r) oacc[t][r] *= alpha[r];
        short8 pa = *(const short8*)&Ps[w][ln][lq * 8];
#pragma unroll
        for (int t = 0; t < 8; ++t) {
            short8 bv = *(const short8*)&Vs[t * 16 + ln][lq * 8];
            oacc[t] = __builtin_amdgcn_mfma_f32_16x16x32_bf16(pa, bv, oacc[t], 0, 0, 0);
        }
    }
    float linv[4];
#pragma unroll
    for (int r = 0; r < 4; ++r) linv[r] = 1.0f / l_run[r];
#pragma unroll
    for (int t = 0; t < 8; ++t)
#pragma unroll
        for (int r = 0; r < 4; ++r) {
            int row = q0 + lq * 4 + r;
            if (row < Lq)
                O[(size_t)row * C_DIM + h * D_HEAD + t * 16 + ln] = f2bf(oacc[t][r] * linv[r]);
        }
}

// ---------------- bf16 MFMA GEMM with optional split-K ----------------
// C = A[M][K] @ BT[N][K]^T (+bias). 128x128 tile, BK=32, 4 waves 2x2,
// global_load_lds width-16 staging, 2-phase double-buffered pipeline:
// issue next K-step's global_load_lds BEFORE computing the current one;
// one __syncthreads() per K-step (its vmcnt(0) drain lands after the MFMAs).
// Buffer read at step t is rewritten at step t+2 -> two barriers apart, safe.
// blockIdx.z selects K-chunk of size Kc.
// atomic=1: atomicAdd partial into bias-pre-initialized Cf.
// gelu=1 (non-atomic): tanh-gelu -> bf16 Cb.
__global__ __launch_bounds__(256) void k_gemm_bf16(const unsigned short* __restrict__ A,
                                                   const unsigned short* __restrict__ BT,
                                                   const float* __restrict__ bias,
                                                   float* __restrict__ Cf,
                                                   unsigned short* __restrict__ Cb,
                                                   int M, int N, int K, int Kc,
                                                   int gelu, int atomic) {
    __shared__ __align__(16) unsigned short As[2][128 * 32];
    __shared__ __align__(16) unsigned short Bs[2][128 * 32];
    const int tid = threadIdx.x;
    const int lane = tid & 63;
    const int w = tid >> 6;
    const int ln = lane & 15, lq = lane >> 4;
    const int wm = w >> 1, wn = w & 1;
    const int bm = blockIdx.y * 128, bn = blockIdx.x * 128;
    const int kb0 = blockIdx.z * Kc;

    int r0 = tid >> 2, c0 = (tid & 3) * 8;
    int ar0 = bm + r0;      if (ar0 >= M) ar0 = M - 1;
    int ar1 = bm + r0 + 64; if (ar1 >= M) ar1 = M - 1;
    const unsigned short* Ag0 = A + (size_t)ar0 * K + c0;
    const unsigned short* Ag1 = A + (size_t)ar1 * K + c0;
    const unsigned short* Bg0 = BT + (size_t)(bn + r0) * K + c0;
    const unsigned short* Bg1 = BT + (size_t)(bn + r0 + 64) * K + c0;

    f32x4 acc[4][4];
#pragma unroll
    for (int i = 0; i < 4; ++i)
#pragma unroll
        for (int j = 0; j < 4; ++j) acc[i][j] = (f32x4){0.f, 0.f, 0.f, 0.f};

    // stage one BK=32 K-tile into buffer b (4 x global_load_lds dwordx4 / thread)
    auto stage = [&](int b, int kb) {
        GL2LDS(Ag0 + kb, &As[b][tid * 8]);
        GL2LDS(Ag1 + kb, &As[b][2048 + tid * 8]);
        GL2LDS(Bg0 + kb, &Bs[b][tid * 8]);
        GL2LDS(Bg1 + kb, &Bs[b][2048 + tid * 8]);
    };
    // compute one BK=32 K-tile from buffer b (8 ds_read_b128 + 16 MFMA / wave)
    auto compute = [&](int b) {
        short8 af[4], bfv[4];
#pragma unroll
        for (int mi = 0; mi < 4; ++mi)
            af[mi] = *(const short8*)&As[b][(wm * 64 + mi * 16 + ln) * 32 + lq * 8];
#pragma unroll
        for (int ni = 0; ni < 4; ++ni)
            bfv[ni] = *(const short8*)&Bs[b][(wn * 64 + ni * 16 + ln) * 32 + lq * 8];
#pragma unroll
        for (int mi = 0; mi < 4; ++mi)
#pragma unroll
            for (int ni = 0; ni < 4; ++ni)
                acc[mi][ni] = __builtin_amdgcn_mfma_f32_16x16x32_bf16(af[mi], bfv[ni],
                                                                      acc[mi][ni], 0, 0, 0);
    };

    const int nk = Kc >> 5;
    stage(0, kb0);
    __syncthreads();
    // unrolled by 2 so buffer indices are compile-time constants
    for (int t = 0; t < nk; t += 2) {
        if (t + 1 < nk) stage(1, kb0 + (t + 1) * 32);   // prefetch -> buf1
        compute(0);                                      // compute  <- buf0
        __syncthreads();                                 // vmcnt(0)+lgkmcnt(0)+barrier
        if (t + 1 >= nk) break;
        if (t + 2 < nk) stage(0, kb0 + (t + 2) * 32);   // prefetch -> buf0
        compute(1);                                      // compute  <- buf1
        __syncthreads();
    }

#pragma unroll
    for (int ni = 0; ni < 4; ++ni) {
        int col = bn + wn * 64 + ni * 16 + ln;
        float bv = atomic ? 0.f : bias[col];
#pragma unroll
        for (int mi = 0; mi < 4; ++mi) {
#pragma unroll
            for (int r = 0; r < 4; ++r) {
                int row = bm + wm * 64 + mi * 16 + lq * 4 + r;
                if (row >= M) continue;
                if (atomic) {
                    atomicAdd(Cf + (size_t)row * N + col, acc[mi][ni][r]);
                } else if (gelu) {
                    float v = acc[mi][ni][r] + bv;
                    float u = 0.7978845608028654f * (v + 0.044715f * v * v * v);
                    float ex = __expf(2.f * u);
                    float t = 1.f - 2.f / (ex + 1.f);   // tanh(u), overflow-safe
                    Cb[(size_t)row * N + col] = f2bf(0.5f * v * (1.f + t));
                } else {
                    Cf[(size_t)row * N + col] = acc[mi][ni][r] + bv;
                }
            }
        }
    }
}

// ---------------- host launch ----------------
extern "C" void kernel_launch(void* const* d_in, const int* in_sizes, int n_in,
                              void* d_out, int out_size, void* d_ws, size_t ws_size,
                              hipStream_t stream) {
    const float* x          = (const float*)d_in[0];
    const float* e          = (const float*)d_in[1];
    const float* context    = (const float*)d_in[2];
    const float* freqs      = (const float*)d_in[3];
    const float* modulation = (const float*)d_in[7];
    const float* sa_q_w = (const float*)d_in[8];
    const float* sa_q_b = (const float*)d_in[9];
    const float* sa_k_w = (const float*)d_in[10];
    const float* sa_k_b = (const float*)d_in[11];
    const float* sa_v_w = (const float*)d_in[12];
    const float* sa_v_b = (const float*)d_in[13];
    const float* sa_o_w = (const float*)d_in[14];
    const float* sa_o_b = (const float*)d_in[15];
    const float* sa_nq  = (const float*)d_in[16];
    const float* sa_nk  = (const float*)d_in[17];
    const float* ca_q_w = (const float*)d_in[18];
    const float* ca_q_b = (const float*)d_in[19];
    const float* ca_k_w = (const float*)d_in[20];
    const float* ca_k_b = (const float*)d_in[21];
    const float* ca_v_w = (const float*)d_in[22];
    const float* ca_v_b = (const float*)d_in[23];
    const float* ca_o_w = (const float*)d_in[24];
    const float* ca_o_b = (const float*)d_in[25];
    const float* ca_nq  = (const float*)d_in[26];
    const float* ca_nk  = (const float*)d_in[27];
    const float* ffn_w1 = (const float*)d_in[28];
    const float* ffn_b1 = (const float*)d_in[29];
    const float* ffn_w2 = (const float*)d_in[30];
    const float* ffn_b2 = (const float*)d_in[31];

    // ---- workspace layout (~173 MB) ----
    const size_t LC = (size_t)L_SEQ * C_DIM;            // 3,686,400
    const size_t WMAX = (size_t)C_DIM * FF_DIM;         // 13,762,560
    char* p = (char*)d_ws;
    float* ev   = (float*)p;            p += 6 * C_DIM * sizeof(float);
    float* Bcat = (float*)p;            p += 3 * C_DIM * sizeof(float);
    float* Xcur = (float*)p;            p += LC * sizeof(float);
    float* Ebuf = (float*)p;            p += LC * sizeof(float);
    float* QKV  = (float*)p;            p += 3 * LC * sizeof(float);  // fused qkv out
    unsigned short* Ab = (unsigned short*)p;  p += LC * sizeof(short);
    unsigned short* Xb = (unsigned short*)p;  p += LC * sizeof(short);
    unsigned short* Qb = (unsigned short*)p;  p += LC * sizeof(short);
    unsigned short* Kb = (unsigned short*)p;  p += LC * sizeof(short);
    unsigned short* Vt = (unsigned short*)p;  p += LC * sizeof(short);
    unsigned short* Ob = (unsigned short*)p;  p += LC * sizeof(short);
    unsigned short* W0 = (unsigned short*)p;  p += WMAX * sizeof(short);
    unsigned short* W1 = (unsigned short*)p;  p += WMAX * sizeof(short);
    unsigned short* Fb = (unsigned short*)QKV;   // [2400][8960] bf16 = 43.0 MB < 44.2 MB
    float* Pq    = QKV;                          // ca_q out [2400][1536] fp32
    float* ctxKV = QKV + LC;                     // [512][3072] fp32

    const int nLC = (int)LC;
    const float SCALE = 0.08838834764831845f;   // 1/sqrt(128)
    dim3 blk(256);
    dim3 g_qkv(4608 / 128, 19, 1);                      // 36 x 19 = 684 blocks
    dim3 g_proj_s4(C_DIM / 128, 19, 4);                 // 12 x 19 x 4 = 912 blocks
    dim3 g_ctxkv_s4(3072 / 128, L_CTX / 128, 4);        // 24 x 4 x 4 = 384 blocks
    dim3 g_ff1(FF_DIM / 128, 19, 1);                    // 70 x 19 = 1330 blocks
    dim3 g_attn((L_SEQ + 63) / 64, N_HEADS);            // 38 x 12
    dim3 g_vt_s(L_SEQ / 32, N_HEADS, 4);
    dim3 g_vt_c(L_CTX / 32, N_HEADS, 4);
    dim3 g_wt_cc(C_DIM / 32, C_DIM / 32);
    dim3 g_wt_w1(C_DIM / 32, FF_DIM / 32);
    dim3 g_wt_w2(FF_DIM / 32, C_DIM / 32);
    dim3 g_half(nLC / 512);
    dim3 g_init_cc(nLC / 1024);                         // 4 elems/thread
    dim3 g_init_kv(L_CTX * 3072 / 1024);

    k_embed<<<dim3((6 * C_DIM + 255) / 256), blk, 0, stream>>>(modulation, e, ev, 6 * C_DIM);

    // ---- phase 1: self-attention ----
    k_catbias<<<dim3((3 * C_DIM + 255) / 256), blk, 0, stream>>>(Bcat, sa_q_b, sa_k_b, sa_v_b,
                                                                 C_DIM, 3 * C_DIM);
    k_wt<<<g_wt_cc, blk, 0, stream>>>(sa_q_w, W0, C_DIM, C_DIM);
    k_wt<<<g_wt_cc, blk, 0, stream>>>(sa_k_w, W0 + (size_t)C_DIM * C_DIM, C_DIM, C_DIM);
    k_wt<<<g_wt_cc, blk, 0, stream>>>(sa_v_w, W0 + (size_t)2 * C_DIM * C_DIM, C_DIM, C_DIM);
    k_lnmod_bf16<<<dim3(L_SEQ), blk, 0, stream>>>(x, ev, 0, 1, Ab);
    k_gemm_bf16<<<g_qkv, blk, 0, stream>>>(Ab, W0, Bcat, QKV, nullptr,
                                           L_SEQ, 4608, C_DIM, C_DIM, 0, 0);
    k_wt<<<g_wt_cc, blk, 0, stream>>>(sa_o_w, W1, C_DIM, C_DIM);
    k_rms_rope_bf16<<<dim3(L_SEQ), blk, 0, stream>>>(QKV, sa_nq, freqs, 1, SCALE, Qb, 4608);
    k_rms_rope_bf16<<<dim3(L_SEQ), blk, 0, stream>>>(QKV + C_DIM, sa_nk, freqs, 1, 1.0f, Kb, 4608);
    k_vt<<<g_vt_s, blk, 0, stream>>>(QKV + 2 * C_DIM, Vt, L_SEQ, 4608);
    k_attn_mfma<<<g_attn, blk, 0, stream>>>(Qb, Kb, Vt, Ob, L_SEQ, L_SEQ);
    k_initbias<<<g_init_cc, blk, 0, stream>>>(Ebuf, sa_o_b, nLC, C_DIM);
    k_gemm_bf16<<<g_proj_s4, blk, 0, stream>>>(Ob, W1, nullptr, Ebuf, nullptr,
                                               L_SEQ, C_DIM, C_DIM, 384, 0, 1);
    k_resid2<<<g_half, blk, 0, stream>>>(x, Ebuf, ev, 2, Xcur, Xb, nLC);

    // ---- phase 2: cross-attention ----
    k_wt<<<g_wt_cc, blk, 0, stream>>>(ca_q_w, W0, C_DIM, C_DIM);
    k_wt<<<g_wt_cc, blk, 0, stream>>>(ca_k_w, W1, C_DIM, C_DIM);
    k_wt<<<g_wt_cc, blk, 0, stream>>>(ca_v_w, W1 + (size_t)C_DIM * C_DIM, C_DIM, C_DIM);
    k_tobf<<<dim3(L_CTX * C_DIM / 512), blk, 0, stream>>>(context, Ab, L_CTX * C_DIM);
    k_catbias<<<dim3((2 * C_DIM + 255) / 256), blk, 0, stream>>>(Bcat, ca_k_b, ca_v_b, nullptr,
                                                                 C_DIM, 2 * C_DIM);
    k_initbias<<<g_init_cc, blk, 0, stream>>>(Pq, ca_q_b, nLC, C_DIM);
    k_gemm_bf16<<<g_proj_s4, blk, 0, stream>>>(Xb, W0, nullptr, Pq, nullptr,
                                               L_SEQ, C_DIM, C_DIM, 384, 0, 1);
    k_initbias<<<g_init_kv, blk, 0, stream>>>(ctxKV, Bcat, L_CTX * 3072, 3072);
    k_gemm_bf16<<<g_ctxkv_s4, blk, 0, stream>>>(Ab, W1, nullptr, ctxKV, nullptr,
                                                L_CTX, 3072, C_DIM, 384, 0, 1);
    k_rms_rope_bf16<<<dim3(L_SEQ), blk, 0, stream>>>(Pq, ca_nq, freqs, 0, SCALE, Qb, C_DIM);
    k_rms_rope_bf16<<<dim3(L_CTX), blk, 0, stream>>>(ctxKV, ca_nk, freqs, 0, 1.0f, Kb, 3072);
    k_vt<<<g_vt_c, blk, 0, stream>>>(ctxKV + C_DIM, Vt, L_CTX, 3072);
    k_attn_mfma<<<g_attn, blk, 0, stream>>>(Qb, Kb, Vt, Ob, L_SEQ, L_CTX);
    k_wt<<<g_wt_cc, blk, 0, stream>>>(ca_o_w, W0, C_DIM, C_DIM);
    k_initbias<<<g_init_cc, blk, 0, stream>>>(Ebuf, ca_o_b, nLC, C_DIM);
    k_gemm_bf16<<<g_proj_s4, blk, 0, stream>>>(Ob, W0, nullptr, Ebuf, nullptr,
                                               L_SEQ, C_DIM, C_DIM, 384, 0, 1);
    k_resid2<<<g_half, blk, 0, stream>>>(Xcur, Ebuf, (const float*)nullptr, -1, Xcur, nullptr, nLC);

    // ---- phase 3: FFN ----
    k_wt<<<g_wt_w1, blk, 0, stream>>>(ffn_w1, W1, C_DIM, FF_DIM);
    k_lnmod_bf16<<<dim3(L_SEQ), blk, 0, stream>>>(Xcur, ev, 3, 4, Ab);
    k_gemm_bf16<<<g_ff1, blk, 0, stream>>>(Ab, W1, ffn_b1, nullptr, Fb,
                                           L_SEQ, FF_DIM, C_DIM, C_DIM, 1, 0);
    k_wt<<<g_wt_w2, blk, 0, stream>>>(ffn_w2, W0, FF_DIM, C_DIM);
    k_initbias<<<g_init_cc, blk, 0, stream>>>(Ebuf, ffn_b2, nLC, C_DIM);
    k_gemm_bf16<<<g_proj_s4, blk, 0, stream>>>(Fb, W0, nullptr, Ebuf, nullptr,
                                               L_SEQ, C_DIM, FF_DIM, 2240, 0, 1);
    k_resid2<<<g_half, blk, 0, stream>>>(Xcur, Ebuf, ev, 5, (float*)d_out, nullptr, nLC);
}

// Round 2
// 1155.602 us; speedup vs baseline: 1.3182x; 1.3182x over previous
//
#include <hip/hip_runtime.h>
#include <cstddef>
#include <cstdint>

// ---------------- problem constants ----------------
#define C_DIM   1536
#define L_SEQ   2400
#define L_CTX   512
#define N_HEADS 12
#define D_HEAD  128
#define FF_DIM  8960
#define F_GRID  2
#define H_GRID  30
#define W_GRID  40
#define EPS_F   1e-6f

#define ROPE_P0 22
#define ROPE_P1 43   // p0 + p1

typedef __attribute__((ext_vector_type(8))) short short8;   // 8 bf16 = 4 VGPRs
typedef __attribute__((ext_vector_type(4))) float f32x4;

__device__ inline unsigned short f2bf(float f) {
    union { float f; unsigned int u; } v; v.f = f;
    unsigned int r = v.u + 0x7FFF + ((v.u >> 16) & 1);
    return (unsigned short)(r >> 16);
}

#define GL2LDS(gp, lp) \
    __builtin_amdgcn_global_load_lds((const __attribute__((address_space(1))) void*)(gp), \
                                     (__attribute__((address_space(3))) void*)(lp), 16, 0, 0)

#define VMCNT6() asm volatile("s_waitcnt vmcnt(6)" ::: "memory")
#define VMCNT0() asm volatile("s_waitcnt vmcnt(0)" ::: "memory")
#define LGKM0()  asm volatile("s_waitcnt lgkmcnt(0)" ::: "memory")
#define BAR()    __builtin_amdgcn_s_barrier()

// ---------------- small elementwise kernels ----------------

__global__ __launch_bounds__(256) void k_embed(const float* __restrict__ mod,
                                               const float* __restrict__ e,
                                               float* __restrict__ ev, int n) {
    int i = blockIdx.x * 256 + threadIdx.x;
    if (i < n) ev[i] = mod[i] + e[i];
}

// concat up to 3 bias vectors of length ne into dst
__global__ __launch_bounds__(256) void k_catbias(float* __restrict__ dst,
                                                 const float* __restrict__ b0,
                                                 const float* __restrict__ b1,
                                                 const float* __restrict__ b2,
                                                 int ne, int n) {
    int i = blockIdx.x * 256 + threadIdx.x;
    if (i >= n) return;
    const float* s = (i < ne) ? b0 : (i < 2 * ne) ? b1 : b2;
    dst[i] = s[i % ne];
}

// C[r][c] = bias[c]  (pre-init for split-K atomic accumulation)
__global__ __launch_bounds__(256) void k_initbias(float* __restrict__ C,
                                                  const float* __restrict__ bias,
                                                  int n, int N) {
    int i4 = (blockIdx.x * 256 + threadIdx.x) * 4;
    if (i4 >= n) return;
    int col = i4 % N;
    *(float4*)(C + i4) = *(const float4*)(bias + col);
}

// out = a + b * scale(ev row ei); optional bf16 secondary output. 2 elems/thread.
__global__ __launch_bounds__(256) void k_resid2(const float* __restrict__ a,
                                                const float* __restrict__ b,
                                                const float* __restrict__ ev, int ei,
                                                float* __restrict__ out,
                                                unsigned short* __restrict__ outb, int n) {
    int i = (blockIdx.x * 256 + threadIdx.x) * 2;
    if (i >= n) return;
    int c = i % C_DIM;
    float s0 = 1.f, s1 = 1.f;
    if (ei >= 0) {
        s0 = ev[ei * C_DIM + c];
        s1 = ev[ei * C_DIM + c + 1];
    }
    float2 av = *(const float2*)(a + i);
    float2 bv = *(const float2*)(b + i);
    float o0 = av.x + bv.x * s0;
    float o1 = av.y + bv.y * s1;
    *(float2*)(out + i) = make_float2(o0, o1);
    if (outb) {
        unsigned int pk = (unsigned int)f2bf(o0) | ((unsigned int)f2bf(o1) << 16);
        *(unsigned int*)(outb + i) = pk;
    }
}

// fp32 -> bf16 convert
__global__ __launch_bounds__(256) void k_tobf(const float* __restrict__ X,
                                              unsigned short* __restrict__ Y, int n) {
    int i = (blockIdx.x * 256 + threadIdx.x) * 2;
    if (i >= n) return;
    float2 v = *(const float2*)(X + i);
    unsigned int pk = (unsigned int)f2bf(v.x) | ((unsigned int)f2bf(v.y) << 16);
    *(unsigned int*)(Y + i) = pk;
}

// ---------------- LayerNorm + modulation -> bf16 ----------------
__global__ __launch_bounds__(256) void k_lnmod_bf16(const float* __restrict__ X,
                                                    const float* __restrict__ ev,
                                                    int i0, int i1,
                                                    unsigned short* __restrict__ H) {
    __shared__ float rs[256];
    __shared__ float rs2[256];
    int row = blockIdx.x, tid = threadIdx.x;
    const float* xr = X + (size_t)row * C_DIM;
    float2 vals[3];
    float s = 0.f, s2 = 0.f;
#pragma unroll
    for (int i = 0; i < 3; ++i) {
        float2 v = *(const float2*)(xr + 2 * (tid + 256 * i));
        vals[i] = v;
        s += v.x + v.y; s2 += v.x * v.x + v.y * v.y;
    }
    rs[tid] = s; rs2[tid] = s2;
    __syncthreads();
    for (int st = 128; st > 0; st >>= 1) {
        if (tid < st) { rs[tid] += rs[tid + st]; rs2[tid] += rs2[tid + st]; }
        __syncthreads();
    }
    float mean = rs[0] * (1.0f / C_DIM);
    float var  = rs2[0] * (1.0f / C_DIM) - mean * mean;
    float rinv = rsqrtf(var + EPS_F);
    const float* E0 = ev + (size_t)i0 * C_DIM;
    const float* E1 = ev + (size_t)i1 * C_DIM;
    unsigned short* hr = H + (size_t)row * C_DIM;
#pragma unroll
    for (int i = 0; i < 3; ++i) {
        int c = 2 * (tid + 256 * i);
        float o0 = E0[c]     + (vals[i].x - mean) * rinv * (1.0f + E1[c]);
        float o1 = E0[c + 1] + (vals[i].y - mean) * rinv * (1.0f + E1[c + 1]);
        unsigned int pk = (unsigned int)f2bf(o0) | ((unsigned int)f2bf(o1) << 16);
        *(unsigned int*)(hr + c) = pk;
    }
}

// ---------------- RMSNorm + optional RoPE -> bf16 (strided input) ----------------
__global__ __launch_bounds__(256) void k_rms_rope_bf16(const float* __restrict__ X,
                                                       const float* __restrict__ w,
                                                       const float* __restrict__ freqs,
                                                       int do_rope, float outscale,
                                                       unsigned short* __restrict__ Y,
                                                       int ldx) {
    __shared__ float rs[256];
    int row = blockIdx.x, tid = threadIdx.x;
    const float* xr = X + (size_t)row * ldx;
    float2 vals[3];
    float ss = 0.f;
#pragma unroll
    for (int i = 0; i < 3; ++i) {
        int p = tid + 256 * i;
        float2 v = *(const float2*)(xr + 2 * p);
        vals[i] = v;
        ss += v.x * v.x + v.y * v.y;
    }
    rs[tid] = ss;
    __syncthreads();
    for (int st = 128; st > 0; st >>= 1) {
        if (tid < st) rs[tid] += rs[tid + st];
        __syncthreads();
    }
    float rinv = rsqrtf(rs[0] * (1.0f / C_DIM) + EPS_F);
    int f = row / (H_GRID * W_GRID);
    int rem = row % (H_GRID * W_GRID);
    int hh = rem / W_GRID, ww = rem % W_GRID;
    unsigned short* yr = Y + (size_t)row * C_DIM;
#pragma unroll
    for (int i = 0; i < 3; ++i) {
        int p = tid + 256 * i;
        int c = 2 * p;
        float a = vals[i].x * rinv * w[c];
        float b = vals[i].y * rinv * w[c + 1];
        if (do_rope) {
            int j = p & 63;
            int idx = (j < ROPE_P0) ? f : (j < ROPE_P1) ? hh : ww;
            float cv = freqs[(idx * 64 + j) * 2 + 0];
            float sv = freqs[(idx * 64 + j) * 2 + 1];
            float na = a * cv - b * sv;
            float nb = a * sv + b * cv;
            a = na; b = nb;
        }
        a *= outscale; b *= outscale;
        unsigned int pk = (unsigned int)f2bf(a) | ((unsigned int)f2bf(b) << 16);
        *(unsigned int*)(yr + c) = pk;
    }
}

// ---------------- weight transpose: fp32 [K][N] -> bf16 [N][K] ----------------
__global__ __launch_bounds__(256) void k_wt(const float* __restrict__ W,
                                            unsigned short* __restrict__ WT,
                                            int K, int N) {
    __shared__ float tile[32][33];
    int k0 = blockIdx.x * 32, n0 = blockIdx.y * 32;
    int t = threadIdx.x;
    int r = t >> 3, c4 = (t & 7) * 4;
    float4 v = *(const float4*)(W + (size_t)(k0 + r) * N + n0 + c4);
    tile[r][c4 + 0] = v.x; tile[r][c4 + 1] = v.y;
    tile[r][c4 + 2] = v.z; tile[r][c4 + 3] = v.w;
    __syncthreads();
    int n = t >> 3, k4 = (t & 7) * 4;
    uint2 o;
    o.x = (unsigned int)f2bf(tile[k4 + 0][n]) | ((unsigned int)f2bf(tile[k4 + 1][n]) << 16);
    o.y = (unsigned int)f2bf(tile[k4 + 2][n]) | ((unsigned int)f2bf(tile[k4 + 3][n]) << 16);
    *(uint2*)(WT + (size_t)(n0 + n) * K + k0 + k4) = o;
}

// ---------------- V transpose: fp32 [Lk][ldv] -> bf16 [12][128][Lk] ----------------
__global__ __launch_bounds__(256) void k_vt(const float* __restrict__ V,
                                            unsigned short* __restrict__ Vt, int Lk, int ldv) {
    __shared__ float tile[32][33];
    int k0 = blockIdx.x * 32, h = blockIdx.y, d0 = blockIdx.z * 32;
    int t = threadIdx.x;
    int k = t >> 3, d4 = (t & 7) * 4;
    float4 v = *(const float4*)(V + (size_t)(k0 + k) * ldv + h * D_HEAD + d0 + d4);
    tile[k][d4 + 0] = v.x; tile[k][d4 + 1] = v.y;
    tile[k][d4 + 2] = v.z; tile[k][d4 + 3] = v.w;
    __syncthreads();
    int d = t >> 3, k4 = (t & 7) * 4;
    uint2 o;
    o.x = (unsigned int)f2bf(tile[k4 + 0][d]) | ((unsigned int)f2bf(tile[k4 + 1][d]) << 16);
    o.y = (unsigned int)f2bf(tile[k4 + 2][d]) | ((unsigned int)f2bf(tile[k4 + 3][d]) << 16);
    *(uint2*)(Vt + (size_t)(h * D_HEAD + d0 + d) * Lk + k0 + k4) = o;
}

// ---------------- MFMA flash attention (bf16 in, bf16 out) ----------------
__global__ __launch_bounds__(256) void k_attn_mfma(const unsigned short* __restrict__ Qb,
                                                   const unsigned short* __restrict__ Kb,
                                                   const unsigned short* __restrict__ Vt,
                                                   unsigned short* __restrict__ O,
                                                   int Lq, int Lk) {
    __shared__ __align__(16) unsigned short Ks[32][136];
    __shared__ __align__(16) unsigned short Vs[128][40];
    __shared__ __align__(16) unsigned short Ps[4][16][40];
    const int tid = threadIdx.x;
    const int w = tid >> 6, lane = tid & 63;
    const int ln = lane & 15, lq = lane >> 4;
    const int h = blockIdx.y;
    const int q0 = blockIdx.x * 64 + w * 16;
    int qrow = q0 + ln; if (qrow >= Lq) qrow = Lq - 1;
    short8 qf[4];
#pragma unroll
    for (int c = 0; c < 4; ++c)
        qf[c] = *(const short8*)(Qb + (size_t)qrow * C_DIM + h * D_HEAD + c * 32 + lq * 8);
    f32x4 oacc[8];
#pragma unroll
    for (int t = 0; t < 8; ++t) oacc[t] = (f32x4){0.f, 0.f, 0.f, 0.f};
    float m_run[4] = {-3e38f, -3e38f, -3e38f, -3e38f};
    float l_run[4] = {0.f, 0.f, 0.f, 0.f};
    const float LOG2E = 1.4426950408889634f;

    for (int kb = 0; kb < Lk; kb += 32) {
        __syncthreads();
#pragma unroll
        for (int i = 0; i < 2; ++i) {
            int id = tid + i * 256;
            int r = id >> 4, c = id & 15;
            *(uint4*)&Ks[r][c * 8] =
                *(const uint4*)(Kb + (size_t)(kb + r) * C_DIM + h * D_HEAD + c * 8);
            int d = id >> 2, c2 = id & 3;
            *(uint4*)&Vs[d][c2 * 8] =
                *(const uint4*)(Vt + (size_t)(h * D_HEAD + d) * Lk + kb + c2 * 8);
        }
        __syncthreads();
        f32x4 c0 = (f32x4){0.f, 0.f, 0.f, 0.f};
        f32x4 c1 = (f32x4){0.f, 0.f, 0.f, 0.f};
#pragma unroll
        for (int c = 0; c < 4; ++c) {
            short8 b0 = *(const short8*)&Ks[ln][c * 32 + lq * 8];
            short8 b1 = *(const short8*)&Ks[16 + ln][c * 32 + lq * 8];
            c0 = __builtin_amdgcn_mfma_f32_16x16x32_bf16(qf[c], b0, c0, 0, 0, 0);
            c1 = __builtin_amdgcn_mfma_f32_16x16x32_bf16(qf[c], b1, c1, 0, 0, 0);
        }
        float alpha[4];
#pragma unroll
        for (int r = 0; r < 4; ++r) {
            float mx = fmaxf(c0[r], c1[r]);
            mx = fmaxf(mx, __shfl_xor(mx, 1));
            mx = fmaxf(mx, __shfl_xor(mx, 2));
            mx = fmaxf(mx, __shfl_xor(mx, 4));
            mx = fmaxf(mx, __shfl_xor(mx, 8));
            float mn = fmaxf(m_run[r], mx);
            alpha[r] = exp2f((m_run[r] - mn) * LOG2E);
            float p0 = exp2f((c0[r] - mn) * LOG2E);
            float p1 = exp2f((c1[r] - mn) * LOG2E);
            float s = p0 + p1;
            s += __shfl_xor(s, 1);
            s += __shfl_xor(s, 2);
            s += __shfl_xor(s, 4);
            s += __shfl_xor(s, 8);
            l_run[r] = l_run[r] * alpha[r] + s;
            m_run[r] = mn;
            Ps[w][lq * 4 + r][ln] = f2bf(p0);
            Ps[w][lq * 4 + r][16 + ln] = f2bf(p1);
        }
#pragma unroll
        for (int t = 0; t < 8; ++t)
#pragma unroll
            for (int r = 0; r < 4; ++r) oacc[t][r] *= alpha[r];
        short8 pa = *(const short8*)&Ps[w][ln][lq * 8];
#pragma unroll
        for (int t = 0; t < 8; ++t) {
            short8 bv = *(const short8*)&Vs[t * 16 + ln][lq * 8];
            oacc[t] = __builtin_amdgcn_mfma_f32_16x16x32_bf16(pa, bv, oacc[t], 0, 0, 0);
        }
    }
    float linv[4];
#pragma unroll
    for (int r = 0; r < 4; ++r) linv[r] = 1.0f / l_run[r];
#pragma unroll
    for (int t = 0; t < 8; ++t)
#pragma unroll
        for (int r = 0; r < 4; ++r) {
            int row = q0 + lq * 4 + r;
            if (row < Lq)
                O[(size_t)row * C_DIM + h * D_HEAD + t * 16 + ln] = f2bf(oacc[t][r] * linv[r]);
        }
}

// ---------------- bf16 MFMA GEMM 128x128 (round-0, single-buffer) ----------------
__global__ __launch_bounds__(256) void k_gemm_bf16(const unsigned short* __restrict__ A,
                                                   const unsigned short* __restrict__ BT,
                                                   const float* __restrict__ bias,
                                                   float* __restrict__ Cf,
                                                   unsigned short* __restrict__ Cb,
                                                   int M, int N, int K, int Kc,
                                                   int gelu, int atomic) {
    __shared__ __align__(16) unsigned short As[128 * 32];
    __shared__ __align__(16) unsigned short Bs[128 * 32];
    const int tid = threadIdx.x;
    const int lane = tid & 63;
    const int w = tid >> 6;
    const int ln = lane & 15, lq = lane >> 4;
    const int wm = w >> 1, wn = w & 1;
    const int bm = blockIdx.y * 128, bn = blockIdx.x * 128;
    const int kb0 = blockIdx.z * Kc;

    int r0 = tid >> 2, c0 = (tid & 3) * 8;
    int ar0 = bm + r0;      if (ar0 >= M) ar0 = M - 1;
    int ar1 = bm + r0 + 64; if (ar1 >= M) ar1 = M - 1;
    const unsigned short* Ag0 = A + (size_t)ar0 * K + c0;
    const unsigned short* Ag1 = A + (size_t)ar1 * K + c0;
    const unsigned short* Bg0 = BT + (size_t)(bn + r0) * K + c0;
    const unsigned short* Bg1 = BT + (size_t)(bn + r0 + 64) * K + c0;
    unsigned short* Al0 = As + tid * 8;
    unsigned short* Al1 = As + 2048 + tid * 8;
    unsigned short* Bl0 = Bs + tid * 8;
    unsigned short* Bl1 = Bs + 2048 + tid * 8;

    f32x4 acc[4][4];
#pragma unroll
    for (int i = 0; i < 4; ++i)
#pragma unroll
        for (int j = 0; j < 4; ++j) acc[i][j] = (f32x4){0.f, 0.f, 0.f, 0.f};

    for (int kb = kb0; kb < kb0 + Kc; kb += 32) {
        __syncthreads();
        GL2LDS(Ag0 + kb, Al0);
        GL2LDS(Ag1 + kb, Al1);
        GL2LDS(Bg0 + kb, Bl0);
        GL2LDS(Bg1 + kb, Bl1);
        __syncthreads();
        short8 af[4], bf[4];
#pragma unroll
        for (int mi = 0; mi < 4; ++mi)
            af[mi] = *(const short8*)&As[(wm * 64 + mi * 16 + ln) * 32 + lq * 8];
#pragma unroll
        for (int ni = 0; ni < 4; ++ni)
            bf[ni] = *(const short8*)&Bs[(wn * 64 + ni * 16 + ln) * 32 + lq * 8];
#pragma unroll
        for (int mi = 0; mi < 4; ++mi)
#pragma unroll
            for (int ni = 0; ni < 4; ++ni)
                acc[mi][ni] = __builtin_amdgcn_mfma_f32_16x16x32_bf16(af[mi], bf[ni],
                                                                      acc[mi][ni], 0, 0, 0);
    }

#pragma unroll
    for (int ni = 0; ni < 4; ++ni) {
        int col = bn + wn * 64 + ni * 16 + ln;
        float bv = atomic ? 0.f : bias[col];
#pragma unroll
        for (int mi = 0; mi < 4; ++mi) {
#pragma unroll
            for (int r = 0; r < 4; ++r) {
                int row = bm + wm * 64 + mi * 16 + lq * 4 + r;
                if (row >= M) continue;
                if (atomic) {
                    atomicAdd(Cf + (size_t)row * N + col, acc[mi][ni][r]);
                } else if (gelu) {
                    float v = acc[mi][ni][r] + bv;
                    float u = 0.7978845608028654f * (v + 0.044715f * v * v * v);
                    float ex = __expf(2.f * u);
                    float t = 1.f - 2.f / (ex + 1.f);   // tanh(u), overflow-safe
                    Cb[(size_t)row * N + col] = f2bf(0.5f * v * (1.f + t));
                } else {
                    Cf[(size_t)row * N + col] = acc[mi][ni][r] + bv;
                }
            }
        }
    }
}

// ---------------- 256x256 8-phase bf16 GEMM (T3+T4+T5: counted vmcnt) ----------------
// C = A[M][K] @ BT[N][K]^T. BM=BN=256, BK=64, 512 thr = 8 waves (2M x 4N),
// per-wave 128x64 out (acc[8][4]). LDS 128 KiB: [buf2][A/B][half2][128][64] bf16.
// Iteration = 2 K-tiles (a->buf0, b->buf1), 8 phases; one half-tile (2 gl2lds/thr)
// staged per stage-slot; vmcnt(6) only at end of P4/P8 (3 half-tiles in flight).
// Schedule invariants (verified):
//   stage slots: P1:Ah1(b) P3:Bh0,Bh1(a+2) P4:Ah0(a+2) P5:Ah1(a+2) P7:Bh0(b+2) P8:Ah0,Bh1(b+2)
//   reads: P1:A(a)lo+B(a)lo P2:B(a)hi P3:A(a)hi P5..P7 same for b. Region last-read
//   always >= 1 barrier before its overwrite-stage; end-P4 vmcnt(6) covers tile-b reads
//   (newest needed = Ah1(b)@P1, 6 newer loads = P3+P4); end-P8 vmcnt(6) covers next
//   iter's tile-a reads (newest needed = Ah1(a+2)@P5, 6 newer = P7+P8).
// Tail: last iter -> vmcnt(0); odd NT -> last iter computes tile a only.
__global__ __launch_bounds__(512, 2) void k_gemm256(const unsigned short* __restrict__ A,
                                                    const unsigned short* __restrict__ BT,
                                                    const float* __restrict__ bias,
                                                    float* __restrict__ Cf,
                                                    unsigned short* __restrict__ Cb,
                                                    int M, int N, int K, int Kc,
                                                    int gelu, int atomic) {
    __shared__ __align__(16) unsigned short lds[2][2][2][128 * 64];
    const int tid = threadIdx.x;
    const int wid = tid >> 6, lane = tid & 63;
    const int ln = lane & 15, lq = lane >> 4;
    const int wm = wid >> 2, wn = wid & 3;
    const int bm = blockIdx.y * 256, bn = blockIdx.x * 256;
    const int kb0 = blockIdx.z * Kc;
    const int NT = Kc >> 6;            // 64-wide K tiles in this chunk (>= 2)
    const int NI = (NT + 1) >> 1;

    // staging pointers: 4 row-groups of 64 for A and for B (thread covers 1 row, 16B)
    const int rr = tid >> 3, cc = (tid & 7) * 8;
    const unsigned short* aP[4];
    const unsigned short* bP[4];
#pragma unroll
    for (int g = 0; g < 4; ++g) {
        int ar = bm + g * 64 + rr; if (ar >= M) ar = M - 1;
        aP[g] = A + (size_t)ar * K + cc + kb0;
        bP[g] = BT + (size_t)(bn + g * 64 + rr) * K + cc + kb0;
    }

    f32x4 acc[8][4];
#pragma unroll
    for (int i = 0; i < 8; ++i)
#pragma unroll
        for (int j = 0; j < 4; ++j) acc[i][j] = (f32x4){0.f, 0.f, 0.f, 0.f};

    short8 af[4][2], bf0[2][2], bf1[2][2];

    const unsigned short* A0 = &lds[0][0][wm][0];
    const unsigned short* A1 = &lds[1][0][wm][0];
    const unsigned short* B0 = &lds[0][1][wn >> 1][0];
    const unsigned short* B1 = &lds[1][1][wn >> 1][0];

    // one half-tile = 128 rows x 64 cols bf16 = 16 KB = 2 rounds of 512 thr x 16 B
    auto stgA = [&](unsigned short* dst, int h, int kt) {
        GL2LDS(aP[h * 2 + 0] + (size_t)kt * 64, dst + tid * 8);
        GL2LDS(aP[h * 2 + 1] + (size_t)kt * 64, dst + 4096 + tid * 8);
    };
    auto stgB = [&](unsigned short* dst, int h, int kt) {
        GL2LDS(bP[h * 2 + 0] + (size_t)kt * 64, dst + tid * 8);
        GL2LDS(bP[h * 2 + 1] + (size_t)kt * 64, dst + 4096 + tid * 8);
    };
    auto rdA = [&](const unsigned short* Ab_, int mh) {
#pragma unroll
        for (int m4 = 0; m4 < 4; ++m4)
#pragma unroll
            for (int ks = 0; ks < 2; ++ks)
                af[m4][ks] = *(const short8*)&Ab_[(mh * 64 + m4 * 16 + ln) * 64 + ks * 32 + lq * 8];
    };
    auto rdB = [&](const unsigned short* Bb_, int nh, short8 (&bfX)[2][2]) {
#pragma unroll
        for (int n2 = 0; n2 < 2; ++n2)
#pragma unroll
            for (int ks = 0; ks < 2; ++ks)
                bfX[n2][ks] = *(const short8*)&Bb_[((wn & 1) * 64 + (nh * 2 + n2) * 16 + ln) * 64 +
                                                   ks * 32 + lq * 8];
    };
    auto mm = [&](int mh, int nh, short8 (&bfX)[2][2]) {
        __builtin_amdgcn_s_setprio(1);
#pragma unroll
        for (int m4 = 0; m4 < 4; ++m4)
#pragma unroll
            for (int n2 = 0; n2 < 2; ++n2)
#pragma unroll
                for (int ks = 0; ks < 2; ++ks)
                    acc[mh * 4 + m4][nh * 2 + n2] = __builtin_amdgcn_mfma_f32_16x16x32_bf16(
                        af[m4][ks], bfX[n2][ks], acc[mh * 4 + m4][nh * 2 + n2], 0, 0, 0);
        __builtin_amdgcn_s_setprio(0);
    };

    // ---- prologue: tiles 0 (buf0) and 1 (buf1) except Ah1(1) (staged at P1 of iter 0)
    stgB(&lds[0][1][0][0], 0, 0); stgB(&lds[0][1][1][0], 1, 0);
    stgA(&lds[0][0][0][0], 0, 0);
    stgA(&lds[0][0][1][0], 1, 0);
    stgB(&lds[1][1][0][0], 0, 1);
    stgA(&lds[1][0][0][0], 0, 1); stgB(&lds[1][1][1][0], 1, 1);
    VMCNT6(); BAR();                    // tile0 landed (newest 6 = tile1 partials)

    for (int k0 = 0; k0 < NI; ++k0) {
        const int a = 2 * k0, bT = a + 1;
        const bool last = (k0 == NI - 1);
        const bool hasB = (bT < NT);
        // ---- P1: reads A(a)lo, B(a)lo; stage Ah1(b)
        rdA(A0, 0); rdB(B0, 0, bf0);
        if (hasB) stgA(&lds[1][0][1][0], 1, bT);
        BAR(); LGKM0();
        mm(0, 0, bf0);
        BAR();
        // ---- P2: reads B(a)hi
        rdB(B0, 1, bf1);
        BAR(); LGKM0();
        mm(0, 1, bf1);
        BAR();
        // ---- P3: reads A(a)hi; stage Bh0,Bh1(a+2)
        rdA(A0, 1);
        if (a + 2 < NT) { stgB(&lds[0][1][0][0], 0, a + 2); stgB(&lds[0][1][1][0], 1, a + 2); }
        BAR(); LGKM0();
        mm(1, 1, bf1);
        BAR();
        // ---- P4: stage Ah0(a+2); end-of-phase vmcnt covers tile-b reads
        if (a + 2 < NT) stgA(&lds[0][0][0][0], 0, a + 2);
        BAR();
        mm(1, 0, bf0);
        if (!hasB) { BAR(); break; }
        if (last) { VMCNT0(); } else { VMCNT6(); }
        BAR();
        // ---- P5: reads A(b)lo, B(b)lo; stage Ah1(a+2)
        rdA(A1, 0); rdB(B1, 0, bf0);
        if (a + 2 < NT) stgA(&lds[0][0][1][0], 1, a + 2);
        BAR(); LGKM0();
        mm(0, 0, bf0);
        BAR();
        // ---- P6: reads B(b)hi
        rdB(B1, 1, bf1);
        BAR(); LGKM0();
        mm(0, 1, bf1);
        BAR();
        // ---- P7: reads A(b)hi; stage Bh0(b+2)
        rdA(A1, 1);
        if (bT + 2 < NT) stgB(&lds[1][1][0][0], 0, bT + 2);
        BAR(); LGKM0();
        mm(1, 1, bf1);
        BAR();
        // ---- P8: stage Ah0,Bh1(b+2); end-of-phase vmcnt covers next tile-a reads
        if (bT + 2 < NT) { stgA(&lds[1][0][0][0], 0, bT + 2); stgB(&lds[1][1][1][0], 1, bT + 2); }
        BAR();
        mm(1, 0, bf0);
        if (k0 >= NI - 2) { VMCNT0(); } else { VMCNT6(); }
        BAR();
    }

    // ---- epilogue
#pragma unroll
    for (int ni = 0; ni < 4; ++ni) {
        int col = bn + wn * 64 + ni * 16 + ln;
        float bv = atomic ? 0.f : bias[col];
#pragma unroll
        for (int mi = 0; mi < 8; ++mi) {
#pragma unroll
            for (int r = 0; r < 4; ++r) {
                int row = bm + wm * 128 + mi * 16 + lq * 4 + r;
                if (row >= M) continue;
                if (atomic) {
                    atomicAdd(Cf + (size_t)row * N + col, acc[mi][ni][r]);
                } else if (gelu) {
                    float v = acc[mi][ni][r] + bv;
                    float u = 0.7978845608028654f * (v + 0.044715f * v * v * v);
                    float ex = __expf(2.f * u);
                    float t = 1.f - 2.f / (ex + 1.f);   // tanh(u), overflow-safe
                    Cb[(size_t)row * N + col] = f2bf(0.5f * v * (1.f + t));
                } else {
                    Cf[(size_t)row * N + col] = acc[mi][ni][r] + bv;
                }
            }
        }
    }
}

// ---------------- host launch ----------------
extern "C" void kernel_launch(void* const* d_in, const int* in_sizes, int n_in,
                              void* d_out, int out_size, void* d_ws, size_t ws_size,
                              hipStream_t stream) {
    const float* x          = (const float*)d_in[0];
    const float* e          = (const float*)d_in[1];
    const float* context    = (const float*)d_in[2];
    const float* freqs      = (const float*)d_in[3];
    const float* modulation = (const float*)d_in[7];
    const float* sa_q_w = (const float*)d_in[8];
    const float* sa_q_b = (const float*)d_in[9];
    const float* sa_k_w = (const float*)d_in[10];
    const float* sa_k_b = (const float*)d_in[11];
    const float* sa_v_w = (const float*)d_in[12];
    const float* sa_v_b = (const float*)d_in[13];
    const float* sa_o_w = (const float*)d_in[14];
    const float* sa_o_b = (const float*)d_in[15];
    const float* sa_nq  = (const float*)d_in[16];
    const float* sa_nk  = (const float*)d_in[17];
    const float* ca_q_w = (const float*)d_in[18];
    const float* ca_q_b = (const float*)d_in[19];
    const float* ca_k_w = (const float*)d_in[20];
    const float* ca_k_b = (const float*)d_in[21];
    const float* ca_v_w = (const float*)d_in[22];
    const float* ca_v_b = (const float*)d_in[23];
    const float* ca_o_w = (const float*)d_in[24];
    const float* ca_o_b = (const float*)d_in[25];
    const float* ca_nq  = (const float*)d_in[26];
    const float* ca_nk  = (const float*)d_in[27];
    const float* ffn_w1 = (const float*)d_in[28];
    const float* ffn_b1 = (const float*)d_in[29];
    const float* ffn_w2 = (const float*)d_in[30];
    const float* ffn_b2 = (const float*)d_in[31];

    // ---- workspace layout (~173 MB) ----
    const size_t LC = (size_t)L_SEQ * C_DIM;            // 3,686,400
    const size_t WMAX = (size_t)C_DIM * FF_DIM;         // 13,762,560
    char* p = (char*)d_ws;
    float* ev   = (float*)p;            p += 6 * C_DIM * sizeof(float);
    float* Bcat = (float*)p;            p += 3 * C_DIM * sizeof(float);
    float* Xcur = (float*)p;            p += LC * sizeof(float);
    float* Ebuf = (float*)p;            p += LC * sizeof(float);
    float* QKV  = (float*)p;            p += 3 * LC * sizeof(float);  // fused qkv out
    unsigned short* Ab = (unsigned short*)p;  p += LC * sizeof(short);
    unsigned short* Xb = (unsigned short*)p;  p += LC * sizeof(short);
    unsigned short* Qb = (unsigned short*)p;  p += LC * sizeof(short);
    unsigned short* Kb = (unsigned short*)p;  p += LC * sizeof(short);
    unsigned short* Vt = (unsigned short*)p;  p += LC * sizeof(short);
    unsigned short* Ob = (unsigned short*)p;  p += LC * sizeof(short);
    unsigned short* W0 = (unsigned short*)p;  p += WMAX * sizeof(short);
    unsigned short* W1 = (unsigned short*)p;  p += WMAX * sizeof(short);
    unsigned short* Fb = (unsigned short*)QKV;   // [2400][8960] bf16 = 43.0 MB < 44.2 MB
    float* Pq    = QKV;                          // ca_q out [2400][1536] fp32
    float* ctxKV = QKV + LC;                     // [512][3072] fp32

    const int nLC = (int)LC;
    const float SCALE = 0.08838834764831845f;   // 1/sqrt(128)
    dim3 blk(256);
    dim3 blk512(512);
    dim3 g_qkv(4608 / 128, 19, 1);                      // 36 x 19 = 684 blocks
    dim3 g_proj_s4(C_DIM / 128, 19, 4);                 // 12 x 19 x 4 = 912 blocks
    dim3 g_ctxkv_s4(3072 / 128, L_CTX / 128, 4);        // 24 x 4 x 4 = 384 blocks
    dim3 g_ff1_256(FF_DIM / 256, 10, 1);                // 35 x 10 = 350 blocks (256^2 tile)
    dim3 g_ff2_256(C_DIM / 256, 10, 4);                 // 6 x 10 x 4 = 240 blocks, Kc=2240
    dim3 g_attn((L_SEQ + 63) / 64, N_HEADS);            // 38 x 12
    dim3 g_vt_s(L_SEQ / 32, N_HEADS, 4);
    dim3 g_vt_c(L_CTX / 32, N_HEADS, 4);
    dim3 g_wt_cc(C_DIM / 32, C_DIM / 32);
    dim3 g_wt_w1(C_DIM / 32, FF_DIM / 32);
    dim3 g_wt_w2(FF_DIM / 32, C_DIM / 32);
    dim3 g_half(nLC / 512);
    dim3 g_init_cc(nLC / 1024);                         // 4 elems/thread
    dim3 g_init_kv(L_CTX * 3072 / 1024);

    k_embed<<<dim3((6 * C_DIM + 255) / 256), blk, 0, stream>>>(modulation, e, ev, 6 * C_DIM);

    // ---- phase 1: self-attention ----
    k_catbias<<<dim3((3 * C_DIM + 255) / 256), blk, 0, stream>>>(Bcat, sa_q_b, sa_k_b, sa_v_b,
                                                                 C_DIM, 3 * C_DIM);
    k_wt<<<g_wt_cc, blk, 0, stream>>>(sa_q_w, W0, C_DIM, C_DIM);
    k_wt<<<g_wt_cc, blk, 0, stream>>>(sa_k_w, W0 + (size_t)C_DIM * C_DIM, C_DIM, C_DIM);
    k_wt<<<g_wt_cc, blk, 0, stream>>>(sa_v_w, W0 + (size_t)2 * C_DIM * C_DIM, C_DIM, C_DIM);
    k_lnmod_bf16<<<dim3(L_SEQ), blk, 0, stream>>>(x, ev, 0, 1, Ab);
    k_gemm_bf16<<<g_qkv, blk, 0, stream>>>(Ab, W0, Bcat, QKV, nullptr,
                                           L_SEQ, 4608, C_DIM, C_DIM, 0, 0);
    k_wt<<<g_wt_cc, blk, 0, stream>>>(sa_o_w, W1, C_DIM, C_DIM);
    k_rms_rope_bf16<<<dim3(L_SEQ), blk, 0, stream>>>(QKV, sa_nq, freqs, 1, SCALE, Qb, 4608);
    k_rms_rope_bf16<<<dim3(L_SEQ), blk, 0, stream>>>(QKV + C_DIM, sa_nk, freqs, 1, 1.0f, Kb, 4608);
    k_vt<<<g_vt_s, blk, 0, stream>>>(QKV + 2 * C_DIM, Vt, L_SEQ, 4608);
    k_attn_mfma<<<g_attn, blk, 0, stream>>>(Qb, Kb, Vt, Ob, L_SEQ, L_SEQ);
    k_initbias<<<g_init_cc, blk, 0, stream>>>(Ebuf, sa_o_b, nLC, C_DIM);
    k_gemm_bf16<<<g_proj_s4, blk, 0, stream>>>(Ob, W1, nullptr, Ebuf, nullptr,
                                               L_SEQ, C_DIM, C_DIM, 384, 0, 1);
    k_resid2<<<g_half, blk, 0, stream>>>(x, Ebuf, ev, 2, Xcur, Xb, nLC);

    // ---- phase 2: cross-attention ----
    k_wt<<<g_wt_cc, blk, 0, stream>>>(ca_q_w, W0, C_DIM, C_DIM);
    k_wt<<<g_wt_cc, blk, 0, stream>>>(ca_k_w, W1, C_DIM, C_DIM);
    k_wt<<<g_wt_cc, blk, 0, stream>>>(ca_v_w, W1 + (size_t)C_DIM * C_DIM, C_DIM, C_DIM);
    k_tobf<<<dim3(L_CTX * C_DIM / 512), blk, 0, stream>>>(context, Ab, L_CTX * C_DIM);
    k_catbias<<<dim3((2 * C_DIM + 255) / 256), blk, 0, stream>>>(Bcat, ca_k_b, ca_v_b, nullptr,
                                                                 C_DIM, 2 * C_DIM);
    k_initbias<<<g_init_cc, blk, 0, stream>>>(Pq, ca_q_b, nLC, C_DIM);
    k_gemm_bf16<<<g_proj_s4, blk, 0, stream>>>(Xb, W0, nullptr, Pq, nullptr,
                                               L_SEQ, C_DIM, C_DIM, 384, 0, 1);
    k_initbias<<<g_init_kv, blk, 0, stream>>>(ctxKV, Bcat, L_CTX * 3072, 3072);
    k_gemm_bf16<<<g_ctxkv_s4, blk, 0, stream>>>(Ab, W1, nullptr, ctxKV, nullptr,
                                                L_CTX, 3072, C_DIM, 384, 0, 1);
    k_rms_rope_bf16<<<dim3(L_SEQ), blk, 0, stream>>>(Pq, ca_nq, freqs, 0, SCALE, Qb, C_DIM);
    k_rms_rope_bf16<<<dim3(L_CTX), blk, 0, stream>>>(ctxKV, ca_nk, freqs, 0, 1.0f, Kb, 3072);
    k_vt<<<g_vt_c, blk, 0, stream>>>(ctxKV + C_DIM, Vt, L_CTX, 3072);
    k_attn_mfma<<<g_attn, blk, 0, stream>>>(Qb, Kb, Vt, Ob, L_SEQ, L_CTX);
    k_wt<<<g_wt_cc, blk, 0, stream>>>(ca_o_w, W0, C_DIM, C_DIM);
    k_initbias<<<g_init_cc, blk, 0, stream>>>(Ebuf, ca_o_b, nLC, C_DIM);
    k_gemm_bf16<<<g_proj_s4, blk, 0, stream>>>(Ob, W0, nullptr, Ebuf, nullptr,
                                               L_SEQ, C_DIM, C_DIM, 384, 0, 1);
    k_resid2<<<g_half, blk, 0, stream>>>(Xcur, Ebuf, (const float*)nullptr, -1, Xcur, nullptr, nLC);

    // ---- phase 3: FFN (256^2 8-phase GEMMs) ----
    k_wt<<<g_wt_w1, blk, 0, stream>>>(ffn_w1, W1, C_DIM, FF_DIM);
    k_lnmod_bf16<<<dim3(L_SEQ), blk, 0, stream>>>(Xcur, ev, 3, 4, Ab);
    k_gemm256<<<g_ff1_256, blk512, 0, stream>>>(Ab, W1, ffn_b1, nullptr, Fb,
                                                L_SEQ, FF_DIM, C_DIM, C_DIM, 1, 0);
    k_wt<<<g_wt_w2, blk, 0, stream>>>(ffn_w2, W0, FF_DIM, C_DIM);
    k_initbias<<<g_init_cc, blk, 0, stream>>>(Ebuf, ffn_b2, nLC, C_DIM);
    k_gemm256<<<g_ff2_256, blk512, 0, stream>>>(Fb, W0, nullptr, Ebuf, nullptr,
                                                L_SEQ, C_DIM, FF_DIM, 2240, 0, 1);
    k_resid2<<<g_half, blk, 0, stream>>>(Xcur, Ebuf, ev, 5, (float*)d_out, nullptr, nLC);
}

// Round 3
// 1098.281 us; speedup vs baseline: 1.3870x; 1.0522x over previous
//
#include <hip/hip_runtime.h>
#include <cstddef>
#include <cstdint>

// ---------------- problem constants ----------------
#define C_DIM   1536
#define L_SEQ   2400
#define L_CTX   512
#define N_HEADS 12
#define D_HEAD  128
#define FF_DIM  8960
#define F_GRID  2
#define H_GRID  30
#define W_GRID  40
#define EPS_F   1e-6f

#define ROPE_P0 22
#define ROPE_P1 43   // p0 + p1

typedef __attribute__((ext_vector_type(8))) short short8;   // 8 bf16 = 4 VGPRs
typedef __attribute__((ext_vector_type(4))) float f32x4;

__device__ inline unsigned short f2bf(float f) {
    union { float f; unsigned int u; } v; v.f = f;
    unsigned int r = v.u + 0x7FFF + ((v.u >> 16) & 1);
    return (unsigned short)(r >> 16);
}

#define GL2LDS(gp, lp) \
    __builtin_amdgcn_global_load_lds((const __attribute__((address_space(1))) void*)(gp), \
                                     (__attribute__((address_space(3))) void*)(lp), 16, 0, 0)

#define VMCNT6() asm volatile("s_waitcnt vmcnt(6)" ::: "memory")
#define VMCNT0() asm volatile("s_waitcnt vmcnt(0)" ::: "memory")
#define LGKM0()  asm volatile("s_waitcnt lgkmcnt(0)" ::: "memory")
#define BAR()    __builtin_amdgcn_s_barrier()

// ---------------- small elementwise kernels ----------------

__global__ __launch_bounds__(256) void k_embed(const float* __restrict__ mod,
                                               const float* __restrict__ e,
                                               float* __restrict__ ev, int n) {
    int i = blockIdx.x * 256 + threadIdx.x;
    if (i < n) ev[i] = mod[i] + e[i];
}

// concat up to 3 bias vectors of length ne into dst
__global__ __launch_bounds__(256) void k_catbias(float* __restrict__ dst,
                                                 const float* __restrict__ b0,
                                                 const float* __restrict__ b1,
                                                 const float* __restrict__ b2,
                                                 int ne, int n) {
    int i = blockIdx.x * 256 + threadIdx.x;
    if (i >= n) return;
    const float* s = (i < ne) ? b0 : (i < 2 * ne) ? b1 : b2;
    dst[i] = s[i % ne];
}

// C[r][c] = bias[c]  (pre-init for split-K atomic accumulation)
__global__ __launch_bounds__(256) void k_initbias(float* __restrict__ C,
                                                  const float* __restrict__ bias,
                                                  int n, int N) {
    int i4 = (blockIdx.x * 256 + threadIdx.x) * 4;
    if (i4 >= n) return;
    int col = i4 % N;
    *(float4*)(C + i4) = *(const float4*)(bias + col);
}

// out = a + b * scale(ev row ei); optional bf16 secondary output. 2 elems/thread.
__global__ __launch_bounds__(256) void k_resid2(const float* __restrict__ a,
                                                const float* __restrict__ b,
                                                const float* __restrict__ ev, int ei,
                                                float* __restrict__ out,
                                                unsigned short* __restrict__ outb, int n) {
    int i = (blockIdx.x * 256 + threadIdx.x) * 2;
    if (i >= n) return;
    int c = i % C_DIM;
    float s0 = 1.f, s1 = 1.f;
    if (ei >= 0) {
        s0 = ev[ei * C_DIM + c];
        s1 = ev[ei * C_DIM + c + 1];
    }
    float2 av = *(const float2*)(a + i);
    float2 bv = *(const float2*)(b + i);
    float o0 = av.x + bv.x * s0;
    float o1 = av.y + bv.y * s1;
    *(float2*)(out + i) = make_float2(o0, o1);
    if (outb) {
        unsigned int pk = (unsigned int)f2bf(o0) | ((unsigned int)f2bf(o1) << 16);
        *(unsigned int*)(outb + i) = pk;
    }
}

// fp32 -> bf16 convert
__global__ __launch_bounds__(256) void k_tobf(const float* __restrict__ X,
                                              unsigned short* __restrict__ Y, int n) {
    int i = (blockIdx.x * 256 + threadIdx.x) * 2;
    if (i >= n) return;
    float2 v = *(const float2*)(X + i);
    unsigned int pk = (unsigned int)f2bf(v.x) | ((unsigned int)f2bf(v.y) << 16);
    *(unsigned int*)(Y + i) = pk;
}

// ---------------- LayerNorm + modulation -> bf16 ----------------
__global__ __launch_bounds__(256) void k_lnmod_bf16(const float* __restrict__ X,
                                                    const float* __restrict__ ev,
                                                    int i0, int i1,
                                                    unsigned short* __restrict__ H) {
    __shared__ float rs[256];
    __shared__ float rs2[256];
    int row = blockIdx.x, tid = threadIdx.x;
    const float* xr = X + (size_t)row * C_DIM;
    float2 vals[3];
    float s = 0.f, s2 = 0.f;
#pragma unroll
    for (int i = 0; i < 3; ++i) {
        float2 v = *(const float2*)(xr + 2 * (tid + 256 * i));
        vals[i] = v;
        s += v.x + v.y; s2 += v.x * v.x + v.y * v.y;
    }
    rs[tid] = s; rs2[tid] = s2;
    __syncthreads();
    for (int st = 128; st > 0; st >>= 1) {
        if (tid < st) { rs[tid] += rs[tid + st]; rs2[tid] += rs2[tid + st]; }
        __syncthreads();
    }
    float mean = rs[0] * (1.0f / C_DIM);
    float var  = rs2[0] * (1.0f / C_DIM) - mean * mean;
    float rinv = rsqrtf(var + EPS_F);
    const float* E0 = ev + (size_t)i0 * C_DIM;
    const float* E1 = ev + (size_t)i1 * C_DIM;
    unsigned short* hr = H + (size_t)row * C_DIM;
#pragma unroll
    for (int i = 0; i < 3; ++i) {
        int c = 2 * (tid + 256 * i);
        float o0 = E0[c]     + (vals[i].x - mean) * rinv * (1.0f + E1[c]);
        float o1 = E0[c + 1] + (vals[i].y - mean) * rinv * (1.0f + E1[c + 1]);
        unsigned int pk = (unsigned int)f2bf(o0) | ((unsigned int)f2bf(o1) << 16);
        *(unsigned int*)(hr + c) = pk;
    }
}

// ---------------- RMSNorm + optional RoPE -> bf16 (strided input) ----------------
__global__ __launch_bounds__(256) void k_rms_rope_bf16(const float* __restrict__ X,
                                                       const float* __restrict__ w,
                                                       const float* __restrict__ freqs,
                                                       int do_rope, float outscale,
                                                       unsigned short* __restrict__ Y,
                                                       int ldx) {
    __shared__ float rs[256];
    int row = blockIdx.x, tid = threadIdx.x;
    const float* xr = X + (size_t)row * ldx;
    float2 vals[3];
    float ss = 0.f;
#pragma unroll
    for (int i = 0; i < 3; ++i) {
        int p = tid + 256 * i;
        float2 v = *(const float2*)(xr + 2 * p);
        vals[i] = v;
        ss += v.x * v.x + v.y * v.y;
    }
    rs[tid] = ss;
    __syncthreads();
    for (int st = 128; st > 0; st >>= 1) {
        if (tid < st) rs[tid] += rs[tid + st];
        __syncthreads();
    }
    float rinv = rsqrtf(rs[0] * (1.0f / C_DIM) + EPS_F);
    int f = row / (H_GRID * W_GRID);
    int rem = row % (H_GRID * W_GRID);
    int hh = rem / W_GRID, ww = rem % W_GRID;
    unsigned short* yr = Y + (size_t)row * C_DIM;
#pragma unroll
    for (int i = 0; i < 3; ++i) {
        int p = tid + 256 * i;
        int c = 2 * p;
        float a = vals[i].x * rinv * w[c];
        float b = vals[i].y * rinv * w[c + 1];
        if (do_rope) {
            int j = p & 63;
            int idx = (j < ROPE_P0) ? f : (j < ROPE_P1) ? hh : ww;
            float cv = freqs[(idx * 64 + j) * 2 + 0];
            float sv = freqs[(idx * 64 + j) * 2 + 1];
            float na = a * cv - b * sv;
            float nb = a * sv + b * cv;
            a = na; b = nb;
        }
        a *= outscale; b *= outscale;
        unsigned int pk = (unsigned int)f2bf(a) | ((unsigned int)f2bf(b) << 16);
        *(unsigned int*)(yr + c) = pk;
    }
}

// ---------------- weight transpose: fp32 [K][N] -> bf16 [N][K] ----------------
__global__ __launch_bounds__(256) void k_wt(const float* __restrict__ W,
                                            unsigned short* __restrict__ WT,
                                            int K, int N) {
    __shared__ float tile[32][33];
    int k0 = blockIdx.x * 32, n0 = blockIdx.y * 32;
    int t = threadIdx.x;
    int r = t >> 3, c4 = (t & 7) * 4;
    float4 v = *(const float4*)(W + (size_t)(k0 + r) * N + n0 + c4);
    tile[r][c4 + 0] = v.x; tile[r][c4 + 1] = v.y;
    tile[r][c4 + 2] = v.z; tile[r][c4 + 3] = v.w;
    __syncthreads();
    int n = t >> 3, k4 = (t & 7) * 4;
    uint2 o;
    o.x = (unsigned int)f2bf(tile[k4 + 0][n]) | ((unsigned int)f2bf(tile[k4 + 1][n]) << 16);
    o.y = (unsigned int)f2bf(tile[k4 + 2][n]) | ((unsigned int)f2bf(tile[k4 + 3][n]) << 16);
    *(uint2*)(WT + (size_t)(n0 + n) * K + k0 + k4) = o;
}

// ---------------- V transpose: fp32 [Lk][ldv] -> bf16 [12][128][Lk] ----------------
__global__ __launch_bounds__(256) void k_vt(const float* __restrict__ V,
                                            unsigned short* __restrict__ Vt, int Lk, int ldv) {
    __shared__ float tile[32][33];
    int k0 = blockIdx.x * 32, h = blockIdx.y, d0 = blockIdx.z * 32;
    int t = threadIdx.x;
    int k = t >> 3, d4 = (t & 7) * 4;
    float4 v = *(const float4*)(V + (size_t)(k0 + k) * ldv + h * D_HEAD + d0 + d4);
    tile[k][d4 + 0] = v.x; tile[k][d4 + 1] = v.y;
    tile[k][d4 + 2] = v.z; tile[k][d4 + 3] = v.w;
    __syncthreads();
    int d = t >> 3, k4 = (t & 7) * 4;
    uint2 o;
    o.x = (unsigned int)f2bf(tile[k4 + 0][d]) | ((unsigned int)f2bf(tile[k4 + 1][d]) << 16);
    o.y = (unsigned int)f2bf(tile[k4 + 2][d]) | ((unsigned int)f2bf(tile[k4 + 3][d]) << 16);
    *(uint2*)(Vt + (size_t)(h * D_HEAD + d0 + d) * Lk + k0 + k4) = o;
}

// ---------------- MFMA flash attention (bf16 in, bf16 out) ----------------
__global__ __launch_bounds__(256) void k_attn_mfma(const unsigned short* __restrict__ Qb,
                                                   const unsigned short* __restrict__ Kb,
                                                   const unsigned short* __restrict__ Vt,
                                                   unsigned short* __restrict__ O,
                                                   int Lq, int Lk) {
    __shared__ __align__(16) unsigned short Ks[32][136];
    __shared__ __align__(16) unsigned short Vs[128][40];
    __shared__ __align__(16) unsigned short Ps[4][16][40];
    const int tid = threadIdx.x;
    const int w = tid >> 6, lane = tid & 63;
    const int ln = lane & 15, lq = lane >> 4;
    const int h = blockIdx.y;
    const int q0 = blockIdx.x * 64 + w * 16;
    int qrow = q0 + ln; if (qrow >= Lq) qrow = Lq - 1;
    short8 qf[4];
#pragma unroll
    for (int c = 0; c < 4; ++c)
        qf[c] = *(const short8*)(Qb + (size_t)qrow * C_DIM + h * D_HEAD + c * 32 + lq * 8);
    f32x4 oacc[8];
#pragma unroll
    for (int t = 0; t < 8; ++t) oacc[t] = (f32x4){0.f, 0.f, 0.f, 0.f};
    float m_run[4] = {-3e38f, -3e38f, -3e38f, -3e38f};
    float l_run[4] = {0.f, 0.f, 0.f, 0.f};
    const float LOG2E = 1.4426950408889634f;

    for (int kb = 0; kb < Lk; kb += 32) {
        __syncthreads();
#pragma unroll
        for (int i = 0; i < 2; ++i) {
            int id = tid + i * 256;
            int r = id >> 4, c = id & 15;
            *(uint4*)&Ks[r][c * 8] =
                *(const uint4*)(Kb + (size_t)(kb + r) * C_DIM + h * D_HEAD + c * 8);
            int d = id >> 2, c2 = id & 3;
            *(uint4*)&Vs[d][c2 * 8] =
                *(const uint4*)(Vt + (size_t)(h * D_HEAD + d) * Lk + kb + c2 * 8);
        }
        __syncthreads();
        f32x4 c0 = (f32x4){0.f, 0.f, 0.f, 0.f};
        f32x4 c1 = (f32x4){0.f, 0.f, 0.f, 0.f};
#pragma unroll
        for (int c = 0; c < 4; ++c) {
            short8 b0 = *(const short8*)&Ks[ln][c * 32 + lq * 8];
            short8 b1 = *(const short8*)&Ks[16 + ln][c * 32 + lq * 8];
            c0 = __builtin_amdgcn_mfma_f32_16x16x32_bf16(qf[c], b0, c0, 0, 0, 0);
            c1 = __builtin_amdgcn_mfma_f32_16x16x32_bf16(qf[c], b1, c1, 0, 0, 0);
        }
        float alpha[4];
#pragma unroll
        for (int r = 0; r < 4; ++r) {
            float mx = fmaxf(c0[r], c1[r]);
            mx = fmaxf(mx, __shfl_xor(mx, 1));
            mx = fmaxf(mx, __shfl_xor(mx, 2));
            mx = fmaxf(mx, __shfl_xor(mx, 4));
            mx = fmaxf(mx, __shfl_xor(mx, 8));
            float mn = fmaxf(m_run[r], mx);
            alpha[r] = exp2f((m_run[r] - mn) * LOG2E);
            float p0 = exp2f((c0[r] - mn) * LOG2E);
            float p1 = exp2f((c1[r] - mn) * LOG2E);
            float s = p0 + p1;
            s += __shfl_xor(s, 1);
            s += __shfl_xor(s, 2);
            s += __shfl_xor(s, 4);
            s += __shfl_xor(s, 8);
            l_run[r] = l_run[r] * alpha[r] + s;
            m_run[r] = mn;
            Ps[w][lq * 4 + r][ln] = f2bf(p0);
            Ps[w][lq * 4 + r][16 + ln] = f2bf(p1);
        }
#pragma unroll
        for (int t = 0; t < 8; ++t)
#pragma unroll
            for (int r = 0; r < 4; ++r) oacc[t][r] *= alpha[r];
        short8 pa = *(const short8*)&Ps[w][ln][lq * 8];
#pragma unroll
        for (int t = 0; t < 8; ++t) {
            short8 bv = *(const short8*)&Vs[t * 16 + ln][lq * 8];
            oacc[t] = __builtin_amdgcn_mfma_f32_16x16x32_bf16(pa, bv, oacc[t], 0, 0, 0);
        }
    }
    float linv[4];
#pragma unroll
    for (int r = 0; r < 4; ++r) linv[r] = 1.0f / l_run[r];
#pragma unroll
    for (int t = 0; t < 8; ++t)
#pragma unroll
        for (int r = 0; r < 4; ++r) {
            int row = q0 + lq * 4 + r;
            if (row < Lq)
                O[(size_t)row * C_DIM + h * D_HEAD + t * 16 + ln] = f2bf(oacc[t][r] * linv[r]);
        }
}

// ---------------- bf16 MFMA GEMM 128x128 (round-0, single-buffer) ----------------
__global__ __launch_bounds__(256) void k_gemm_bf16(const unsigned short* __restrict__ A,
                                                   const unsigned short* __restrict__ BT,
                                                   const float* __restrict__ bias,
                                                   float* __restrict__ Cf,
                                                   unsigned short* __restrict__ Cb,
                                                   int M, int N, int K, int Kc,
                                                   int gelu, int atomic) {
    __shared__ __align__(16) unsigned short As[128 * 32];
    __shared__ __align__(16) unsigned short Bs[128 * 32];
    const int tid = threadIdx.x;
    const int lane = tid & 63;
    const int w = tid >> 6;
    const int ln = lane & 15, lq = lane >> 4;
    const int wm = w >> 1, wn = w & 1;
    const int bm = blockIdx.y * 128, bn = blockIdx.x * 128;
    const int kb0 = blockIdx.z * Kc;

    int r0 = tid >> 2, c0 = (tid & 3) * 8;
    int ar0 = bm + r0;      if (ar0 >= M) ar0 = M - 1;
    int ar1 = bm + r0 + 64; if (ar1 >= M) ar1 = M - 1;
    const unsigned short* Ag0 = A + (size_t)ar0 * K + c0;
    const unsigned short* Ag1 = A + (size_t)ar1 * K + c0;
    const unsigned short* Bg0 = BT + (size_t)(bn + r0) * K + c0;
    const unsigned short* Bg1 = BT + (size_t)(bn + r0 + 64) * K + c0;
    unsigned short* Al0 = As + tid * 8;
    unsigned short* Al1 = As + 2048 + tid * 8;
    unsigned short* Bl0 = Bs + tid * 8;
    unsigned short* Bl1 = Bs + 2048 + tid * 8;

    f32x4 acc[4][4];
#pragma unroll
    for (int i = 0; i < 4; ++i)
#pragma unroll
        for (int j = 0; j < 4; ++j) acc[i][j] = (f32x4){0.f, 0.f, 0.f, 0.f};

    for (int kb = kb0; kb < kb0 + Kc; kb += 32) {
        __syncthreads();
        GL2LDS(Ag0 + kb, Al0);
        GL2LDS(Ag1 + kb, Al1);
        GL2LDS(Bg0 + kb, Bl0);
        GL2LDS(Bg1 + kb, Bl1);
        __syncthreads();
        short8 af[4], bf[4];
#pragma unroll
        for (int mi = 0; mi < 4; ++mi)
            af[mi] = *(const short8*)&As[(wm * 64 + mi * 16 + ln) * 32 + lq * 8];
#pragma unroll
        for (int ni = 0; ni < 4; ++ni)
            bf[ni] = *(const short8*)&Bs[(wn * 64 + ni * 16 + ln) * 32 + lq * 8];
#pragma unroll
        for (int mi = 0; mi < 4; ++mi)
#pragma unroll
            for (int ni = 0; ni < 4; ++ni)
                acc[mi][ni] = __builtin_amdgcn_mfma_f32_16x16x32_bf16(af[mi], bf[ni],
                                                                      acc[mi][ni], 0, 0, 0);
    }

#pragma unroll
    for (int ni = 0; ni < 4; ++ni) {
        int col = bn + wn * 64 + ni * 16 + ln;
        float bv = atomic ? 0.f : bias[col];
#pragma unroll
        for (int mi = 0; mi < 4; ++mi) {
#pragma unroll
            for (int r = 0; r < 4; ++r) {
                int row = bm + wm * 64 + mi * 16 + lq * 4 + r;
                if (row >= M) continue;
                if (atomic) {
                    atomicAdd(Cf + (size_t)row * N + col, acc[mi][ni][r]);
                } else if (gelu) {
                    float v = acc[mi][ni][r] + bv;
                    float u = 0.7978845608028654f * (v + 0.044715f * v * v * v);
                    float ex = __expf(2.f * u);
                    float t = 1.f - 2.f / (ex + 1.f);   // tanh(u), overflow-safe
                    Cb[(size_t)row * N + col] = f2bf(0.5f * v * (1.f + t));
                } else {
                    Cf[(size_t)row * N + col] = acc[mi][ni][r] + bv;
                }
            }
        }
    }
}

// ---------------- 256x256 8-phase bf16 GEMM (T2+T3+T4+T5) ----------------
// C = A[M][K] @ BT[N][K]^T. BM=BN=256, BK=64, 512 thr = 8 waves (2M x 4N),
// per-wave 128x64 out (acc[8][4]). LDS 128 KiB: [buf2][A/B][half2][128][64] bf16.
// T2 LDS swizzle (rule #21: both-sides): LDS dest stays LINEAR (global_load_lds
// writes base+lane*16); the global SOURCE column-slot is pre-swizzled
// (slot ^= row&7) and the ds_read applies the same involution
// (sl = (ks*4+lq) ^ (ln&7)). Post-swizzle, each ds_read_b128 spreads its 64
// lanes 8 lanes-per-16B-slot across all 32 banks = minimum 8 cyc (2-way free).
// Iteration = 2 K-tiles (a->buf0, b->buf1), 8 phases; one half-tile (2 gl2lds/thr)
// staged per stage-slot; vmcnt(6) only at end of P4/P8 (3 half-tiles in flight).
// Schedule invariants (verified r2, passed):
//   stage slots: P1:Ah1(b) P3:Bh0,Bh1(a+2) P4:Ah0(a+2) P5:Ah1(a+2) P7:Bh0(b+2) P8:Ah0,Bh1(b+2)
//   reads: P1:A(a)lo+B(a)lo P2:B(a)hi P3:A(a)hi P5..P7 same for b. Region last-read
//   always >= 1 barrier before its overwrite-stage; end-P4 vmcnt(6) covers tile-b reads;
//   end-P8 vmcnt(6) covers next iter's tile-a reads.
// Tail: last iter -> vmcnt(0); odd NT -> last iter computes tile a only.
__global__ __launch_bounds__(512, 2) void k_gemm256(const unsigned short* __restrict__ A,
                                                    const unsigned short* __restrict__ BT,
                                                    const float* __restrict__ bias,
                                                    float* __restrict__ Cf,
                                                    unsigned short* __restrict__ Cb,
                                                    int M, int N, int K, int Kc,
                                                    int gelu, int atomic) {
    __shared__ __align__(16) unsigned short lds[2][2][2][128 * 64];
    const int tid = threadIdx.x;
    const int wid = tid >> 6, lane = tid & 63;
    const int ln = lane & 15, lq = lane >> 4;
    const int wm = wid >> 2, wn = wid & 3;
    const int bm = blockIdx.y * 256, bn = blockIdx.x * 256;
    const int kb0 = blockIdx.z * Kc;
    const int NT = Kc >> 6;            // 64-wide K tiles in this chunk (>= 2)
    const int NI = (NT + 1) >> 1;

    // staging: thread covers row rr (of a 64-row group), 16B col-slot (tid&7).
    // T2: pre-swizzle the GLOBAL source slot so linear LDS holds swizzled data.
    const int rr = tid >> 3;
    const int cc = (((tid & 7) ^ (rr & 7)) * 8);
    const unsigned short* aP[4];
    const unsigned short* bP[4];
#pragma unroll
    for (int g = 0; g < 4; ++g) {
        int ar = bm + g * 64 + rr; if (ar >= M) ar = M - 1;
        aP[g] = A + (size_t)ar * K + cc + kb0;
        bP[g] = BT + (size_t)(bn + g * 64 + rr) * K + cc + kb0;
    }

    f32x4 acc[8][4];
#pragma unroll
    for (int i = 0; i < 8; ++i)
#pragma unroll
        for (int j = 0; j < 4; ++j) acc[i][j] = (f32x4){0.f, 0.f, 0.f, 0.f};

    short8 af[4][2], bf0[2][2], bf1[2][2];

    const unsigned short* A0 = &lds[0][0][wm][0];
    const unsigned short* A1 = &lds[1][0][wm][0];
    const unsigned short* B0 = &lds[0][1][wn >> 1][0];
    const unsigned short* B1 = &lds[1][1][wn >> 1][0];

    // one half-tile = 128 rows x 64 cols bf16 = 16 KB = 2 rounds of 512 thr x 16 B
    auto stgA = [&](unsigned short* dst, int h, int kt) {
        GL2LDS(aP[h * 2 + 0] + (size_t)kt * 64, dst + tid * 8);
        GL2LDS(aP[h * 2 + 1] + (size_t)kt * 64, dst + 4096 + tid * 8);
    };
    auto stgB = [&](unsigned short* dst, int h, int kt) {
        GL2LDS(bP[h * 2 + 0] + (size_t)kt * 64, dst + tid * 8);
        GL2LDS(bP[h * 2 + 1] + (size_t)kt * 64, dst + 4096 + tid * 8);
    };
    // swizzled ds_read: slot = (ks*4+lq) ^ (row&7); row&7 == ln&7 here
    auto rdA = [&](const unsigned short* Ab_, int mh) {
#pragma unroll
        for (int m4 = 0; m4 < 4; ++m4) {
            const int row = mh * 64 + m4 * 16 + ln;
#pragma unroll
            for (int ks = 0; ks < 2; ++ks) {
                const int sl = (ks * 4 + lq) ^ (ln & 7);
                af[m4][ks] = *(const short8*)&Ab_[row * 64 + sl * 8];
            }
        }
    };
    auto rdB = [&](const unsigned short* Bb_, int nh, short8 (&bfX)[2][2]) {
#pragma unroll
        for (int n2 = 0; n2 < 2; ++n2) {
            const int row = (wn & 1) * 64 + (nh * 2 + n2) * 16 + ln;
#pragma unroll
            for (int ks = 0; ks < 2; ++ks) {
                const int sl = (ks * 4 + lq) ^ (ln & 7);
                bfX[n2][ks] = *(const short8*)&Bb_[row * 64 + sl * 8];
            }
        }
    };
    auto mm = [&](int mh, int nh, short8 (&bfX)[2][2]) {
        __builtin_amdgcn_s_setprio(1);
#pragma unroll
        for (int m4 = 0; m4 < 4; ++m4)
#pragma unroll
            for (int n2 = 0; n2 < 2; ++n2)
#pragma unroll
                for (int ks = 0; ks < 2; ++ks)
                    acc[mh * 4 + m4][nh * 2 + n2] = __builtin_amdgcn_mfma_f32_16x16x32_bf16(
                        af[m4][ks], bfX[n2][ks], acc[mh * 4 + m4][nh * 2 + n2], 0, 0, 0);
        __builtin_amdgcn_s_setprio(0);
    };

    // ---- prologue: tiles 0 (buf0) and 1 (buf1) except Ah1(1) (staged at P1 of iter 0)
    stgB(&lds[0][1][0][0], 0, 0); stgB(&lds[0][1][1][0], 1, 0);
    stgA(&lds[0][0][0][0], 0, 0);
    stgA(&lds[0][0][1][0], 1, 0);
    stgB(&lds[1][1][0][0], 0, 1);
    stgA(&lds[1][0][0][0], 0, 1); stgB(&lds[1][1][1][0], 1, 1);
    VMCNT6(); BAR();                    // tile0 landed (newest 6 = tile1 partials)

    for (int k0 = 0; k0 < NI; ++k0) {
        const int a = 2 * k0, bT = a + 1;
        const bool last = (k0 == NI - 1);
        const bool hasB = (bT < NT);
        // ---- P1: reads A(a)lo, B(a)lo; stage Ah1(b)
        rdA(A0, 0); rdB(B0, 0, bf0);
        if (hasB) stgA(&lds[1][0][1][0], 1, bT);
        BAR(); LGKM0();
        mm(0, 0, bf0);
        BAR();
        // ---- P2: reads B(a)hi
        rdB(B0, 1, bf1);
        BAR(); LGKM0();
        mm(0, 1, bf1);
        BAR();
        // ---- P3: reads A(a)hi; stage Bh0,Bh1(a+2)
        rdA(A0, 1);
        if (a + 2 < NT) { stgB(&lds[0][1][0][0], 0, a + 2); stgB(&lds[0][1][1][0], 1, a + 2); }
        BAR(); LGKM0();
        mm(1, 1, bf1);
        BAR();
        // ---- P4: stage Ah0(a+2); end-of-phase vmcnt covers tile-b reads
        if (a + 2 < NT) stgA(&lds[0][0][0][0], 0, a + 2);
        BAR();
        mm(1, 0, bf0);
        if (!hasB) { BAR(); break; }
        if (last) { VMCNT0(); } else { VMCNT6(); }
        BAR();
        // ---- P5: reads A(b)lo, B(b)lo; stage Ah1(a+2)
        rdA(A1, 0); rdB(B1, 0, bf0);
        if (a + 2 < NT) stgA(&lds[0][0][1][0], 1, a + 2);
        BAR(); LGKM0();
        mm(0, 0, bf0);
        BAR();
        // ---- P6: reads B(b)hi
        rdB(B1, 1, bf1);
        BAR(); LGKM0();
        mm(0, 1, bf1);
        BAR();
        // ---- P7: reads A(b)hi; stage Bh0(b+2)
        rdA(A1, 1);
        if (bT + 2 < NT) stgB(&lds[1][1][0][0], 0, bT + 2);
        BAR(); LGKM0();
        mm(1, 1, bf1);
        BAR();
        // ---- P8: stage Ah0,Bh1(b+2); end-of-phase vmcnt covers next tile-a reads
        if (bT + 2 < NT) { stgA(&lds[1][0][0][0], 0, bT + 2); stgB(&lds[1][1][1][0], 1, bT + 2); }
        BAR();
        mm(1, 0, bf0);
        if (k0 >= NI - 2) { VMCNT0(); } else { VMCNT6(); }
        BAR();
    }

    // ---- epilogue
#pragma unroll
    for (int ni = 0; ni < 4; ++ni) {
        int col = bn + wn * 64 + ni * 16 + ln;
        float bv = atomic ? 0.f : bias[col];
#pragma unroll
        for (int mi = 0; mi < 8; ++mi) {
#pragma unroll
            for (int r = 0; r < 4; ++r) {
                int row = bm + wm * 128 + mi * 16 + lq * 4 + r;
                if (row >= M) continue;
                if (atomic) {
                    atomicAdd(Cf + (size_t)row * N + col, acc[mi][ni][r]);
                } else if (gelu) {
                    float v = acc[mi][ni][r] + bv;
                    float u = 0.7978845608028654f * (v + 0.044715f * v * v * v);
                    float ex = __expf(2.f * u);
                    float t = 1.f - 2.f / (ex + 1.f);   // tanh(u), overflow-safe
                    Cb[(size_t)row * N + col] = f2bf(0.5f * v * (1.f + t));
                } else {
                    Cf[(size_t)row * N + col] = acc[mi][ni][r] + bv;
                }
            }
        }
    }
}

// ---------------- host launch ----------------
extern "C" void kernel_launch(void* const* d_in, const int* in_sizes, int n_in,
                              void* d_out, int out_size, void* d_ws, size_t ws_size,
                              hipStream_t stream) {
    const float* x          = (const float*)d_in[0];
    const float* e          = (const float*)d_in[1];
    const float* context    = (const float*)d_in[2];
    const float* freqs      = (const float*)d_in[3];
    const float* modulation = (const float*)d_in[7];
    const float* sa_q_w = (const float*)d_in[8];
    const float* sa_q_b = (const float*)d_in[9];
    const float* sa_k_w = (const float*)d_in[10];
    const float* sa_k_b = (const float*)d_in[11];
    const float* sa_v_w = (const float*)d_in[12];
    const float* sa_v_b = (const float*)d_in[13];
    const float* sa_o_w = (const float*)d_in[14];
    const float* sa_o_b = (const float*)d_in[15];
    const float* sa_nq  = (const float*)d_in[16];
    const float* sa_nk  = (const float*)d_in[17];
    const float* ca_q_w = (const float*)d_in[18];
    const float* ca_q_b = (const float*)d_in[19];
    const float* ca_k_w = (const float*)d_in[20];
    const float* ca_k_b = (const float*)d_in[21];
    const float* ca_v_w = (const float*)d_in[22];
    const float* ca_v_b = (const float*)d_in[23];
    const float* ca_o_w = (const float*)d_in[24];
    const float* ca_o_b = (const float*)d_in[25];
    const float* ca_nq  = (const float*)d_in[26];
    const float* ca_nk  = (const float*)d_in[27];
    const float* ffn_w1 = (const float*)d_in[28];
    const float* ffn_b1 = (const float*)d_in[29];
    const float* ffn_w2 = (const float*)d_in[30];
    const float* ffn_b2 = (const float*)d_in[31];

    // ---- workspace layout (~173 MB) ----
    const size_t LC = (size_t)L_SEQ * C_DIM;            // 3,686,400
    const size_t WMAX = (size_t)C_DIM * FF_DIM;         // 13,762,560
    char* p = (char*)d_ws;
    float* ev   = (float*)p;            p += 6 * C_DIM * sizeof(float);
    float* Bcat = (float*)p;            p += 3 * C_DIM * sizeof(float);
    float* Xcur = (float*)p;            p += LC * sizeof(float);
    float* Ebuf = (float*)p;            p += LC * sizeof(float);
    float* QKV  = (float*)p;            p += 3 * LC * sizeof(float);  // fused qkv out
    unsigned short* Ab = (unsigned short*)p;  p += LC * sizeof(short);
    unsigned short* Xb = (unsigned short*)p;  p += LC * sizeof(short);
    unsigned short* Qb = (unsigned short*)p;  p += LC * sizeof(short);
    unsigned short* Kb = (unsigned short*)p;  p += LC * sizeof(short);
    unsigned short* Vt = (unsigned short*)p;  p += LC * sizeof(short);
    unsigned short* Ob = (unsigned short*)p;  p += LC * sizeof(short);
    unsigned short* W0 = (unsigned short*)p;  p += WMAX * sizeof(short);
    unsigned short* W1 = (unsigned short*)p;  p += WMAX * sizeof(short);
    unsigned short* Fb = (unsigned short*)QKV;   // [2400][8960] bf16 = 43.0 MB < 44.2 MB
    float* Pq    = QKV;                          // ca_q out [2400][1536] fp32
    float* ctxKV = QKV + LC;                     // [512][3072] fp32

    const int nLC = (int)LC;
    const float SCALE = 0.08838834764831845f;   // 1/sqrt(128)
    dim3 blk(256);
    dim3 blk512(512);
    dim3 g_qkv_256(4608 / 256, 10, 1);                  // 18 x 10 = 180 blocks (256^2)
    dim3 g_proj_s4(C_DIM / 128, 19, 4);                 // 12 x 19 x 4 = 912 blocks
    dim3 g_ctxkv_s4(3072 / 128, L_CTX / 128, 4);        // 24 x 4 x 4 = 384 blocks
    dim3 g_ff1_256(FF_DIM / 256, 10, 1);                // 35 x 10 = 350 blocks (256^2 tile)
    dim3 g_ff2_256(C_DIM / 256, 10, 4);                 // 6 x 10 x 4 = 240 blocks, Kc=2240
    dim3 g_attn((L_SEQ + 63) / 64, N_HEADS);            // 38 x 12
    dim3 g_vt_s(L_SEQ / 32, N_HEADS, 4);
    dim3 g_vt_c(L_CTX / 32, N_HEADS, 4);
    dim3 g_wt_cc(C_DIM / 32, C_DIM / 32);
    dim3 g_wt_w1(C_DIM / 32, FF_DIM / 32);
    dim3 g_wt_w2(FF_DIM / 32, C_DIM / 32);
    dim3 g_half(nLC / 512);
    dim3 g_init_cc(nLC / 1024);                         // 4 elems/thread
    dim3 g_init_kv(L_CTX * 3072 / 1024);

    k_embed<<<dim3((6 * C_DIM + 255) / 256), blk, 0, stream>>>(modulation, e, ev, 6 * C_DIM);

    // ---- phase 1: self-attention ----
    k_catbias<<<dim3((3 * C_DIM + 255) / 256), blk, 0, stream>>>(Bcat, sa_q_b, sa_k_b, sa_v_b,
                                                                 C_DIM, 3 * C_DIM);
    k_wt<<<g_wt_cc, blk, 0, stream>>>(sa_q_w, W0, C_DIM, C_DIM);
    k_wt<<<g_wt_cc, blk, 0, stream>>>(sa_k_w, W0 + (size_t)C_DIM * C_DIM, C_DIM, C_DIM);
    k_wt<<<g_wt_cc, blk, 0, stream>>>(sa_v_w, W0 + (size_t)2 * C_DIM * C_DIM, C_DIM, C_DIM);
    k_lnmod_bf16<<<dim3(L_SEQ), blk, 0, stream>>>(x, ev, 0, 1, Ab);
    k_gemm256<<<g_qkv_256, blk512, 0, stream>>>(Ab, W0, Bcat, QKV, nullptr,
                                                L_SEQ, 4608, C_DIM, C_DIM, 0, 0);
    k_wt<<<g_wt_cc, blk, 0, stream>>>(sa_o_w, W1, C_DIM, C_DIM);
    k_rms_rope_bf16<<<dim3(L_SEQ), blk, 0, stream>>>(QKV, sa_nq, freqs, 1, SCALE, Qb, 4608);
    k_rms_rope_bf16<<<dim3(L_SEQ), blk, 0, stream>>>(QKV + C_DIM, sa_nk, freqs, 1, 1.0f, Kb, 4608);
    k_vt<<<g_vt_s, blk, 0, stream>>>(QKV + 2 * C_DIM, Vt, L_SEQ, 4608);
    k_attn_mfma<<<g_attn, blk, 0, stream>>>(Qb, Kb, Vt, Ob, L_SEQ, L_SEQ);
    k_initbias<<<g_init_cc, blk, 0, stream>>>(Ebuf, sa_o_b, nLC, C_DIM);
    k_gemm_bf16<<<g_proj_s4, blk, 0, stream>>>(Ob, W1, nullptr, Ebuf, nullptr,
                                               L_SEQ, C_DIM, C_DIM, 384, 0, 1);
    k_resid2<<<g_half, blk, 0, stream>>>(x, Ebuf, ev, 2, Xcur, Xb, nLC);

    // ---- phase 2: cross-attention ----
    k_wt<<<g_wt_cc, blk, 0, stream>>>(ca_q_w, W0, C_DIM, C_DIM);
    k_wt<<<g_wt_cc, blk, 0, stream>>>(ca_k_w, W1, C_DIM, C_DIM);
    k_wt<<<g_wt_cc, blk, 0, stream>>>(ca_v_w, W1 + (size_t)C_DIM * C_DIM, C_DIM, C_DIM);
    k_tobf<<<dim3(L_CTX * C_DIM / 512), blk, 0, stream>>>(context, Ab, L_CTX * C_DIM);
    k_catbias<<<dim3((2 * C_DIM + 255) / 256), blk, 0, stream>>>(Bcat, ca_k_b, ca_v_b, nullptr,
                                                                 C_DIM, 2 * C_DIM);
    k_initbias<<<g_init_cc, blk, 0, stream>>>(Pq, ca_q_b, nLC, C_DIM);
    k_gemm_bf16<<<g_proj_s4, blk, 0, stream>>>(Xb, W0, nullptr, Pq, nullptr,
                                               L_SEQ, C_DIM, C_DIM, 384, 0, 1);
    k_initbias<<<g_init_kv, blk, 0, stream>>>(ctxKV, Bcat, L_CTX * 3072, 3072);
    k_gemm_bf16<<<g_ctxkv_s4, blk, 0, stream>>>(Ab, W1, nullptr, ctxKV, nullptr,
                                                L_CTX, 3072, C_DIM, 384, 0, 1);
    k_rms_rope_bf16<<<dim3(L_SEQ), blk, 0, stream>>>(Pq, ca_nq, freqs, 0, SCALE, Qb, C_DIM);
    k_rms_rope_bf16<<<dim3(L_CTX), blk, 0, stream>>>(ctxKV, ca_nk, freqs, 0, 1.0f, Kb, 3072);
    k_vt<<<g_vt_c, blk, 0, stream>>>(ctxKV + C_DIM, Vt, L_CTX, 3072);
    k_attn_mfma<<<g_attn, blk, 0, stream>>>(Qb, Kb, Vt, Ob, L_SEQ, L_CTX);
    k_wt<<<g_wt_cc, blk, 0, stream>>>(ca_o_w, W0, C_DIM, C_DIM);
    k_initbias<<<g_init_cc, blk, 0, stream>>>(Ebuf, ca_o_b, nLC, C_DIM);
    k_gemm_bf16<<<g_proj_s4, blk, 0, stream>>>(Ob, W0, nullptr, Ebuf, nullptr,
                                               L_SEQ, C_DIM, C_DIM, 384, 0, 1);
    k_resid2<<<g_half, blk, 0, stream>>>(Xcur, Ebuf, (const float*)nullptr, -1, Xcur, nullptr, nLC);

    // ---- phase 3: FFN (256^2 8-phase GEMMs) ----
    k_wt<<<g_wt_w1, blk, 0, stream>>>(ffn_w1, W1, C_DIM, FF_DIM);
    k_lnmod_bf16<<<dim3(L_SEQ), blk, 0, stream>>>(Xcur, ev, 3, 4, Ab);
    k_gemm256<<<g_ff1_256, blk512, 0, stream>>>(Ab, W1, ffn_b1, nullptr, Fb,
                                                L_SEQ, FF_DIM, C_DIM, C_DIM, 1, 0);
    k_wt<<<g_wt_w2, blk, 0, stream>>>(ffn_w2, W0, FF_DIM, C_DIM);
    k_initbias<<<g_init_cc, blk, 0, stream>>>(Ebuf, ffn_b2, nLC, C_DIM);
    k_gemm256<<<g_ff2_256, blk512, 0, stream>>>(Fb, W0, nullptr, Ebuf, nullptr,
                                                L_SEQ, C_DIM, FF_DIM, 2240, 0, 1);
    k_resid2<<<g_half, blk, 0, stream>>>(Xcur, Ebuf, ev, 5, (float*)d_out, nullptr, nLC);
}

// Round 5
// 1041.750 us; speedup vs baseline: 1.4622x; 1.0543x over previous
//
#include <hip/hip_runtime.h>
#include <cstddef>
#include <cstdint>

// ---------------- problem constants ----------------
#define C_DIM   1536
#define L_SEQ   2400
#define L_CTX   512
#define N_HEADS 12
#define D_HEAD  128
#define FF_DIM  8960
#define F_GRID  2
#define H_GRID  30
#define W_GRID  40
#define EPS_F   1e-6f

#define ROPE_P0 22
#define ROPE_P1 43   // p0 + p1

typedef __attribute__((ext_vector_type(8))) short short8;   // 8 bf16 = 4 VGPRs
typedef __attribute__((ext_vector_type(4))) float f32x4;

__device__ inline unsigned short f2bf(float f) {
    union { float f; unsigned int u; } v; v.f = f;
    unsigned int r = v.u + 0x7FFF + ((v.u >> 16) & 1);
    return (unsigned short)(r >> 16);
}

#define GL2LDS(gp, lp) \
    __builtin_amdgcn_global_load_lds((const __attribute__((address_space(1))) void*)(gp), \
                                     (__attribute__((address_space(3))) void*)(lp), 16, 0, 0)

#define VMCNT6() asm volatile("s_waitcnt vmcnt(6)" ::: "memory")
#define VMCNT0() asm volatile("s_waitcnt vmcnt(0)" ::: "memory")
#define LGKM0()  asm volatile("s_waitcnt lgkmcnt(0)" ::: "memory")
#define BAR()    __builtin_amdgcn_s_barrier()

// ---------------- small elementwise kernels ----------------

__global__ __launch_bounds__(256) void k_embed(const float* __restrict__ mod,
                                               const float* __restrict__ e,
                                               float* __restrict__ ev, int n) {
    int i = blockIdx.x * 256 + threadIdx.x;
    if (i < n) ev[i] = mod[i] + e[i];
}

// concat up to 3 bias vectors of length ne into dst
__global__ __launch_bounds__(256) void k_catbias(float* __restrict__ dst,
                                                 const float* __restrict__ b0,
                                                 const float* __restrict__ b1,
                                                 const float* __restrict__ b2,
                                                 int ne, int n) {
    int i = blockIdx.x * 256 + threadIdx.x;
    if (i >= n) return;
    const float* s = (i < ne) ? b0 : (i < 2 * ne) ? b1 : b2;
    dst[i] = s[i % ne];
}

// C[r][c] = bias[c]  (pre-init for split-K atomic accumulation)
__global__ __launch_bounds__(256) void k_initbias(float* __restrict__ C,
                                                  const float* __restrict__ bias,
                                                  int n, int N) {
    int i4 = (blockIdx.x * 256 + threadIdx.x) * 4;
    if (i4 >= n) return;
    int col = i4 % N;
    *(float4*)(C + i4) = *(const float4*)(bias + col);
}

// out = a + b * scale(ev row ei); optional bf16 secondary output. 2 elems/thread.
__global__ __launch_bounds__(256) void k_resid2(const float* __restrict__ a,
                                                const float* __restrict__ b,
                                                const float* __restrict__ ev, int ei,
                                                float* __restrict__ out,
                                                unsigned short* __restrict__ outb, int n) {
    int i = (blockIdx.x * 256 + threadIdx.x) * 2;
    if (i >= n) return;
    int c = i % C_DIM;
    float s0 = 1.f, s1 = 1.f;
    if (ei >= 0) {
        s0 = ev[ei * C_DIM + c];
        s1 = ev[ei * C_DIM + c + 1];
    }
    float2 av = *(const float2*)(a + i);
    float2 bv = *(const float2*)(b + i);
    float o0 = av.x + bv.x * s0;
    float o1 = av.y + bv.y * s1;
    *(float2*)(out + i) = make_float2(o0, o1);
    if (outb) {
        unsigned int pk = (unsigned int)f2bf(o0) | ((unsigned int)f2bf(o1) << 16);
        *(unsigned int*)(outb + i) = pk;
    }
}

// fp32 -> bf16 convert
__global__ __launch_bounds__(256) void k_tobf(const float* __restrict__ X,
                                              unsigned short* __restrict__ Y, int n) {
    int i = (blockIdx.x * 256 + threadIdx.x) * 2;
    if (i >= n) return;
    float2 v = *(const float2*)(X + i);
    unsigned int pk = (unsigned int)f2bf(v.x) | ((unsigned int)f2bf(v.y) << 16);
    *(unsigned int*)(Y + i) = pk;
}

// ---------------- LayerNorm + modulation -> bf16 ----------------
__global__ __launch_bounds__(256) void k_lnmod_bf16(const float* __restrict__ X,
                                                    const float* __restrict__ ev,
                                                    int i0, int i1,
                                                    unsigned short* __restrict__ H) {
    __shared__ float rs[256];
    __shared__ float rs2[256];
    int row = blockIdx.x, tid = threadIdx.x;
    const float* xr = X + (size_t)row * C_DIM;
    float2 vals[3];
    float s = 0.f, s2 = 0.f;
#pragma unroll
    for (int i = 0; i < 3; ++i) {
        float2 v = *(const float2*)(xr + 2 * (tid + 256 * i));
        vals[i] = v;
        s += v.x + v.y; s2 += v.x * v.x + v.y * v.y;
    }
    rs[tid] = s; rs2[tid] = s2;
    __syncthreads();
    for (int st = 128; st > 0; st >>= 1) {
        if (tid < st) { rs[tid] += rs[tid + st]; rs2[tid] += rs2[tid + st]; }
        __syncthreads();
    }
    float mean = rs[0] * (1.0f / C_DIM);
    float var  = rs2[0] * (1.0f / C_DIM) - mean * mean;
    float rinv = rsqrtf(var + EPS_F);
    const float* E0 = ev + (size_t)i0 * C_DIM;
    const float* E1 = ev + (size_t)i1 * C_DIM;
    unsigned short* hr = H + (size_t)row * C_DIM;
#pragma unroll
    for (int i = 0; i < 3; ++i) {
        int c = 2 * (tid + 256 * i);
        float o0 = E0[c]     + (vals[i].x - mean) * rinv * (1.0f + E1[c]);
        float o1 = E0[c + 1] + (vals[i].y - mean) * rinv * (1.0f + E1[c + 1]);
        unsigned int pk = (unsigned int)f2bf(o0) | ((unsigned int)f2bf(o1) << 16);
        *(unsigned int*)(hr + c) = pk;
    }
}

// ---------------- RMSNorm + optional RoPE -> bf16 (strided input) ----------------
__global__ __launch_bounds__(256) void k_rms_rope_bf16(const float* __restrict__ X,
                                                       const float* __restrict__ w,
                                                       const float* __restrict__ freqs,
                                                       int do_rope, float outscale,
                                                       unsigned short* __restrict__ Y,
                                                       int ldx) {
    __shared__ float rs[256];
    int row = blockIdx.x, tid = threadIdx.x;
    const float* xr = X + (size_t)row * ldx;
    float2 vals[3];
    float ss = 0.f;
#pragma unroll
    for (int i = 0; i < 3; ++i) {
        int p = tid + 256 * i;
        float2 v = *(const float2*)(xr + 2 * p);
        vals[i] = v;
        ss += v.x * v.x + v.y * v.y;
    }
    rs[tid] = ss;
    __syncthreads();
    for (int st = 128; st > 0; st >>= 1) {
        if (tid < st) rs[tid] += rs[tid + st];
        __syncthreads();
    }
    float rinv = rsqrtf(rs[0] * (1.0f / C_DIM) + EPS_F);
    int f = row / (H_GRID * W_GRID);
    int rem = row % (H_GRID * W_GRID);
    int hh = rem / W_GRID, ww = rem % W_GRID;
    unsigned short* yr = Y + (size_t)row * C_DIM;
#pragma unroll
    for (int i = 0; i < 3; ++i) {
        int p = tid + 256 * i;
        int c = 2 * p;
        float a = vals[i].x * rinv * w[c];
        float b = vals[i].y * rinv * w[c + 1];
        if (do_rope) {
            int j = p & 63;
            int idx = (j < ROPE_P0) ? f : (j < ROPE_P1) ? hh : ww;
            float cv = freqs[(idx * 64 + j) * 2 + 0];
            float sv = freqs[(idx * 64 + j) * 2 + 1];
            float na = a * cv - b * sv;
            float nb = a * sv + b * cv;
            a = na; b = nb;
        }
        a *= outscale; b *= outscale;
        unsigned int pk = (unsigned int)f2bf(a) | ((unsigned int)f2bf(b) << 16);
        *(unsigned int*)(yr + c) = pk;
    }
}

// ---------------- weight transpose: fp32 [K][N] -> bf16 [N][K] ----------------
__global__ __launch_bounds__(256) void k_wt(const float* __restrict__ W,
                                            unsigned short* __restrict__ WT,
                                            int K, int N) {
    __shared__ float tile[32][33];
    int k0 = blockIdx.x * 32, n0 = blockIdx.y * 32;
    int t = threadIdx.x;
    int r = t >> 3, c4 = (t & 7) * 4;
    float4 v = *(const float4*)(W + (size_t)(k0 + r) * N + n0 + c4);
    tile[r][c4 + 0] = v.x; tile[r][c4 + 1] = v.y;
    tile[r][c4 + 2] = v.z; tile[r][c4 + 3] = v.w;
    __syncthreads();
    int n = t >> 3, k4 = (t & 7) * 4;
    uint2 o;
    o.x = (unsigned int)f2bf(tile[k4 + 0][n]) | ((unsigned int)f2bf(tile[k4 + 1][n]) << 16);
    o.y = (unsigned int)f2bf(tile[k4 + 2][n]) | ((unsigned int)f2bf(tile[k4 + 3][n]) << 16);
    *(uint2*)(WT + (size_t)(n0 + n) * K + k0 + k4) = o;
}

// ---------------- V transpose: fp32 [Lk][ldv] -> bf16 [12][128][Lk] ----------------
__global__ __launch_bounds__(256) void k_vt(const float* __restrict__ V,
                                            unsigned short* __restrict__ Vt, int Lk, int ldv) {
    __shared__ float tile[32][33];
    int k0 = blockIdx.x * 32, h = blockIdx.y, d0 = blockIdx.z * 32;
    int t = threadIdx.x;
    int k = t >> 3, d4 = (t & 7) * 4;
    float4 v = *(const float4*)(V + (size_t)(k0 + k) * ldv + h * D_HEAD + d0 + d4);
    tile[k][d4 + 0] = v.x; tile[k][d4 + 1] = v.y;
    tile[k][d4 + 2] = v.z; tile[k][d4 + 3] = v.w;
    __syncthreads();
    int d = t >> 3, k4 = (t & 7) * 4;
    uint2 o;
    o.x = (unsigned int)f2bf(tile[k4 + 0][d]) | ((unsigned int)f2bf(tile[k4 + 1][d]) << 16);
    o.y = (unsigned int)f2bf(tile[k4 + 2][d]) | ((unsigned int)f2bf(tile[k4 + 3][d]) << 16);
    *(uint2*)(Vt + (size_t)(h * D_HEAD + d0 + d) * Lk + k0 + k4) = o;
}

// ---------------- MFMA flash attention v2 ----------------
// 4 waves x 16 q-rows, KVBLK=64. K,V staged via global_load_lds with both-sides
// XOR swizzle (rule #21): LDS dest linear, global source col-slot ^= (row&7),
// ds_read applies same involution. Defer-max (T13, THR=8). Tail (Lk%64==32):
// groups 2,3 masked via uniform gv2; staged tail addresses CLAMPED in-bounds
// (clamped garbage stays masked — never reaches live accumulators).
// LDS: Ks 16KB + Vs 16KB + Ps 4x16x68x2B = 8.5KB -> 41.5KB = 3 blocks/CU.
__global__ __launch_bounds__(256) void k_attn_mfma(const unsigned short* __restrict__ Qb,
                                                   const unsigned short* __restrict__ Kb,
                                                   const unsigned short* __restrict__ Vt,
                                                   unsigned short* __restrict__ O,
                                                   int Lq, int Lk) {
    __shared__ __align__(16) unsigned short Ks[64 * 128];
    __shared__ __align__(16) unsigned short Vs[128 * 64];
    __shared__ __align__(16) unsigned short Ps[4][16][68];
    const int tid = threadIdx.x;
    const int w = tid >> 6, lane = tid & 63;
    const int ln = lane & 15, lq = lane >> 4;
    const int h = blockIdx.y;
    const int q0 = blockIdx.x * 64 + w * 16;
    int qrow = q0 + ln; if (qrow >= Lq) qrow = Lq - 1;
    short8 qf[4];
#pragma unroll
    for (int c = 0; c < 4; ++c)
        qf[c] = *(const short8*)(Qb + (size_t)qrow * C_DIM + h * D_HEAD + c * 32 + lq * 8);

    // K staging: 1024 16B chunks, 4 rounds; thread covers rows rowK[j], slot sk.
    // Source slot pre-swizzled ^ (row&7) (invariant across rounds: rows step by 16).
    const int r0k = tid >> 4, sk = tid & 15;
    const int kxor = r0k & 7;                       // < 8: slot stays in 0..15
    const int kcol = h * D_HEAD + (sk ^ kxor) * 8;
    int rowK[4];
    unsigned short* dK[4];
#pragma unroll
    for (int j = 0; j < 4; ++j) {
        rowK[j] = r0k + 16 * j;
        dK[j] = (unsigned short*)Ks + ((size_t)tid + 256 * j) * 8;
    }
    // V staging: thread covers d-rows dRow[j], slot sv (8 slots of 8 per 64-col row).
    const int d0v = tid >> 3, sv = tid & 7;
    const int vxor = d0v & 7;
    const int vslot = (sv ^ vxor) * 8;              // 0..56
    int dRow[4];
    unsigned short* dV[4];
#pragma unroll
    for (int j = 0; j < 4; ++j) {
        dRow[j] = h * D_HEAD + d0v + 32 * j;
        dV[j] = (unsigned short*)Vs + ((size_t)tid + 256 * j) * 8;
    }

    f32x4 oacc[8];
#pragma unroll
    for (int t = 0; t < 8; ++t) oacc[t] = (f32x4){0.f, 0.f, 0.f, 0.f};
    float m_run[4] = {-3e38f, -3e38f, -3e38f, -3e38f};
    float l_run[4] = {0.f, 0.f, 0.f, 0.f};
    const float LOG2E = 1.4426950408889634f;
    const int lx = ln & 7;

    for (int kb = 0; kb < Lk; kb += 64) {
        const bool gv2 = (kb + 32) < Lk;   // groups 2,3 valid (Lk % 32 == 0 always)
        __syncthreads();
#pragma unroll
        for (int j = 0; j < 4; ++j) {
            int kr = kb + rowK[j]; if (kr >= Lk) kr = Lk - 1;        // clamp (masked anyway)
            GL2LDS(Kb + (size_t)kr * C_DIM + kcol, dK[j]);
            int vc = kb + vslot; if (vc + 8 > Lk) vc = Lk - 8;       // clamp (masked anyway)
            GL2LDS(Vt + (size_t)dRow[j] * Lk + vc, dV[j]);
        }
        __syncthreads();   // drains vmcnt(0): staged data visible

        // ---- QK^T: S[q=lq*4+r][k=g*16+ln], K=128 over c
        f32x4 c0 = (f32x4){0.f,0.f,0.f,0.f}, c1 = c0, c2 = c0, c3 = c0;
#pragma unroll
        for (int c = 0; c < 4; ++c) {
            const int slt = ((c * 4 + lq) ^ lx) * 8;
            short8 b0 = *(const short8*)&Ks[(size_t)(ln) * 128 + slt];
            short8 b1 = *(const short8*)&Ks[(size_t)(16 + ln) * 128 + slt];
            c0 = __builtin_amdgcn_mfma_f32_16x16x32_bf16(qf[c], b0, c0, 0, 0, 0);
            c1 = __builtin_amdgcn_mfma_f32_16x16x32_bf16(qf[c], b1, c1, 0, 0, 0);
            if (gv2) {
                short8 b2 = *(const short8*)&Ks[(size_t)(32 + ln) * 128 + slt];
                short8 b3 = *(const short8*)&Ks[(size_t)(48 + ln) * 128 + slt];
                c2 = __builtin_amdgcn_mfma_f32_16x16x32_bf16(qf[c], b2, c2, 0, 0, 0);
                c3 = __builtin_amdgcn_mfma_f32_16x16x32_bf16(qf[c], b3, c3, 0, 0, 0);
            }
        }

        // ---- online softmax with defer-max (THR=8)
#pragma unroll
        for (int r = 0; r < 4; ++r) {
            float mx = fmaxf(c0[r], c1[r]);
            if (gv2) mx = fmaxf(mx, fmaxf(c2[r], c3[r]));
            mx = fmaxf(mx, __shfl_xor(mx, 1));
            mx = fmaxf(mx, __shfl_xor(mx, 2));
            mx = fmaxf(mx, __shfl_xor(mx, 4));
            mx = fmaxf(mx, __shfl_xor(mx, 8));
            float mn = m_run[r];
            float a = 1.f;
            if (__any(mx > mn + 8.f)) {
                float m2 = fmaxf(mn, mx);
                a = exp2f((mn - m2) * LOG2E);
                mn = m2;
                m_run[r] = m2;
#pragma unroll
                for (int t = 0; t < 8; ++t) oacc[t][r] *= a;
            }
            float p0 = exp2f((c0[r] - mn) * LOG2E);
            float p1 = exp2f((c1[r] - mn) * LOG2E);
            float p2 = gv2 ? exp2f((c2[r] - mn) * LOG2E) : 0.f;
            float p3 = gv2 ? exp2f((c3[r] - mn) * LOG2E) : 0.f;
            float s = p0 + p1 + p2 + p3;
            s += __shfl_xor(s, 1);
            s += __shfl_xor(s, 2);
            s += __shfl_xor(s, 4);
            s += __shfl_xor(s, 8);
            l_run[r] = l_run[r] * a + s;
            Ps[w][lq * 4 + r][ln] = f2bf(p0);
            Ps[w][lq * 4 + r][16 + ln] = f2bf(p1);
            if (gv2) {
                Ps[w][lq * 4 + r][32 + ln] = f2bf(p2);
                Ps[w][lq * 4 + r][48 + ln] = f2bf(p3);
            }
        }

        // ---- PV: O += P[q][k] * V-fragments (swizzled V reads)
        short8 pa0 = *(const short8*)&Ps[w][ln][lq * 8];
#pragma unroll
        for (int t = 0; t < 8; ++t) {
            short8 bv = *(const short8*)&Vs[(size_t)(t * 16 + ln) * 64 + ((lq ^ lx) * 8)];
            oacc[t] = __builtin_amdgcn_mfma_f32_16x16x32_bf16(pa0, bv, oacc[t], 0, 0, 0);
        }
        if (gv2) {
            short8 pa1 = *(const short8*)&Ps[w][ln][32 + lq * 8];
#pragma unroll
            for (int t = 0; t < 8; ++t) {
                short8 bv = *(const short8*)&Vs[(size_t)(t * 16 + ln) * 64 + (((4 + lq) ^ lx) * 8)];
                oacc[t] = __builtin_amdgcn_mfma_f32_16x16x32_bf16(pa1, bv, oacc[t], 0, 0, 0);
            }
        }
    }
    float linv[4];
#pragma unroll
    for (int r = 0; r < 4; ++r) linv[r] = 1.0f / l_run[r];
#pragma unroll
    for (int t = 0; t < 8; ++t)
#pragma unroll
        for (int r = 0; r < 4; ++r) {
            int row = q0 + lq * 4 + r;
            if (row < Lq)
                O[(size_t)row * C_DIM + h * D_HEAD + t * 16 + ln] = f2bf(oacc[t][r] * linv[r]);
        }
}

// ---------------- 256x256 8-phase bf16 GEMM (T2+T3+T4+T5) ----------------
// (unchanged from round 3 — verified passing; all GEMMs route here)
__global__ __launch_bounds__(512, 2) void k_gemm256(const unsigned short* __restrict__ A,
                                                    const unsigned short* __restrict__ BT,
                                                    const float* __restrict__ bias,
                                                    float* __restrict__ Cf,
                                                    unsigned short* __restrict__ Cb,
                                                    int M, int N, int K, int Kc,
                                                    int gelu, int atomic) {
    __shared__ __align__(16) unsigned short lds[2][2][2][128 * 64];
    const int tid = threadIdx.x;
    const int wid = tid >> 6, lane = tid & 63;
    const int ln = lane & 15, lq = lane >> 4;
    const int wm = wid >> 2, wn = wid & 3;
    const int bm = blockIdx.y * 256, bn = blockIdx.x * 256;
    const int kb0 = blockIdx.z * Kc;
    const int NT = Kc >> 6;            // 64-wide K tiles in this chunk (>= 2)
    const int NI = (NT + 1) >> 1;

    const int rr = tid >> 3;
    const int cc = (((tid & 7) ^ (rr & 7)) * 8);
    const unsigned short* aP[4];
    const unsigned short* bP[4];
#pragma unroll
    for (int g = 0; g < 4; ++g) {
        int ar = bm + g * 64 + rr; if (ar >= M) ar = M - 1;
        aP[g] = A + (size_t)ar * K + cc + kb0;
        bP[g] = BT + (size_t)(bn + g * 64 + rr) * K + cc + kb0;
    }

    f32x4 acc[8][4];
#pragma unroll
    for (int i = 0; i < 8; ++i)
#pragma unroll
        for (int j = 0; j < 4; ++j) acc[i][j] = (f32x4){0.f, 0.f, 0.f, 0.f};

    short8 af[4][2], bf0[2][2], bf1[2][2];

    const unsigned short* A0 = &lds[0][0][wm][0];
    const unsigned short* A1 = &lds[1][0][wm][0];
    const unsigned short* B0 = &lds[0][1][wn >> 1][0];
    const unsigned short* B1 = &lds[1][1][wn >> 1][0];

    auto stgA = [&](unsigned short* dst, int h, int kt) {
        GL2LDS(aP[h * 2 + 0] + (size_t)kt * 64, dst + tid * 8);
        GL2LDS(aP[h * 2 + 1] + (size_t)kt * 64, dst + 4096 + tid * 8);
    };
    auto stgB = [&](unsigned short* dst, int h, int kt) {
        GL2LDS(bP[h * 2 + 0] + (size_t)kt * 64, dst + tid * 8);
        GL2LDS(bP[h * 2 + 1] + (size_t)kt * 64, dst + 4096 + tid * 8);
    };
    auto rdA = [&](const unsigned short* Ab_, int mh) {
#pragma unroll
        for (int m4 = 0; m4 < 4; ++m4) {
            const int row = mh * 64 + m4 * 16 + ln;
#pragma unroll
            for (int ks = 0; ks < 2; ++ks) {
                const int sl = (ks * 4 + lq) ^ (ln & 7);
                af[m4][ks] = *(const short8*)&Ab_[row * 64 + sl * 8];
            }
        }
    };
    auto rdB = [&](const unsigned short* Bb_, int nh, short8 (&bfX)[2][2]) {
#pragma unroll
        for (int n2 = 0; n2 < 2; ++n2) {
            const int row = (wn & 1) * 64 + (nh * 2 + n2) * 16 + ln;
#pragma unroll
            for (int ks = 0; ks < 2; ++ks) {
                const int sl = (ks * 4 + lq) ^ (ln & 7);
                bfX[n2][ks] = *(const short8*)&Bb_[row * 64 + sl * 8];
            }
        }
    };
    auto mm = [&](int mh, int nh, short8 (&bfX)[2][2]) {
        __builtin_amdgcn_s_setprio(1);
#pragma unroll
        for (int m4 = 0; m4 < 4; ++m4)
#pragma unroll
            for (int n2 = 0; n2 < 2; ++n2)
#pragma unroll
                for (int ks = 0; ks < 2; ++ks)
                    acc[mh * 4 + m4][nh * 2 + n2] = __builtin_amdgcn_mfma_f32_16x16x32_bf16(
                        af[m4][ks], bfX[n2][ks], acc[mh * 4 + m4][nh * 2 + n2], 0, 0, 0);
        __builtin_amdgcn_s_setprio(0);
    };

    stgB(&lds[0][1][0][0], 0, 0); stgB(&lds[0][1][1][0], 1, 0);
    stgA(&lds[0][0][0][0], 0, 0);
    stgA(&lds[0][0][1][0], 1, 0);
    stgB(&lds[1][1][0][0], 0, 1);
    stgA(&lds[1][0][0][0], 0, 1); stgB(&lds[1][1][1][0], 1, 1);
    VMCNT6(); BAR();

    for (int k0 = 0; k0 < NI; ++k0) {
        const int a = 2 * k0, bT = a + 1;
        const bool last = (k0 == NI - 1);
        const bool hasB = (bT < NT);
        rdA(A0, 0); rdB(B0, 0, bf0);
        if (hasB) stgA(&lds[1][0][1][0], 1, bT);
        BAR(); LGKM0();
        mm(0, 0, bf0);
        BAR();
        rdB(B0, 1, bf1);
        BAR(); LGKM0();
        mm(0, 1, bf1);
        BAR();
        rdA(A0, 1);
        if (a + 2 < NT) { stgB(&lds[0][1][0][0], 0, a + 2); stgB(&lds[0][1][1][0], 1, a + 2); }
        BAR(); LGKM0();
        mm(1, 1, bf1);
        BAR();
        if (a + 2 < NT) stgA(&lds[0][0][0][0], 0, a + 2);
        BAR();
        mm(1, 0, bf0);
        if (!hasB) { BAR(); break; }
        if (last) { VMCNT0(); } else { VMCNT6(); }
        BAR();
        rdA(A1, 0); rdB(B1, 0, bf0);
        if (a + 2 < NT) stgA(&lds[0][0][1][0], 1, a + 2);
        BAR(); LGKM0();
        mm(0, 0, bf0);
        BAR();
        rdB(B1, 1, bf1);
        BAR(); LGKM0();
        mm(0, 1, bf1);
        BAR();
        rdA(A1, 1);
        if (bT + 2 < NT) stgB(&lds[1][1][0][0], 0, bT + 2);
        BAR(); LGKM0();
        mm(1, 1, bf1);
        BAR();
        if (bT + 2 < NT) { stgA(&lds[1][0][0][0], 0, bT + 2); stgB(&lds[1][1][1][0], 1, bT + 2); }
        BAR();
        mm(1, 0, bf0);
        if (k0 >= NI - 2) { VMCNT0(); } else { VMCNT6(); }
        BAR();
    }

#pragma unroll
    for (int ni = 0; ni < 4; ++ni) {
        int col = bn + wn * 64 + ni * 16 + ln;
        float bv = atomic ? 0.f : bias[col];
#pragma unroll
        for (int mi = 0; mi < 8; ++mi) {
#pragma unroll
            for (int r = 0; r < 4; ++r) {
                int row = bm + wm * 128 + mi * 16 + lq * 4 + r;
                if (row >= M) continue;
                if (atomic) {
                    atomicAdd(Cf + (size_t)row * N + col, acc[mi][ni][r]);
                } else if (gelu) {
                    float v = acc[mi][ni][r] + bv;
                    float u = 0.7978845608028654f * (v + 0.044715f * v * v * v);
                    float ex = __expf(2.f * u);
                    float t = 1.f - 2.f / (ex + 1.f);   // tanh(u), overflow-safe
                    Cb[(size_t)row * N + col] = f2bf(0.5f * v * (1.f + t));
                } else {
                    Cf[(size_t)row * N + col] = acc[mi][ni][r] + bv;
                }
            }
        }
    }
}

// ---------------- host launch ----------------
extern "C" void kernel_launch(void* const* d_in, const int* in_sizes, int n_in,
                              void* d_out, int out_size, void* d_ws, size_t ws_size,
                              hipStream_t stream) {
    const float* x          = (const float*)d_in[0];
    const float* e          = (const float*)d_in[1];
    const float* context    = (const float*)d_in[2];
    const float* freqs      = (const float*)d_in[3];
    const float* modulation = (const float*)d_in[7];
    const float* sa_q_w = (const float*)d_in[8];
    const float* sa_q_b = (const float*)d_in[9];
    const float* sa_k_w = (const float*)d_in[10];
    const float* sa_k_b = (const float*)d_in[11];
    const float* sa_v_w = (const float*)d_in[12];
    const float* sa_v_b = (const float*)d_in[13];
    const float* sa_o_w = (const float*)d_in[14];
    const float* sa_o_b = (const float*)d_in[15];
    const float* sa_nq  = (const float*)d_in[16];
    const float* sa_nk  = (const float*)d_in[17];
    const float* ca_q_w = (const float*)d_in[18];
    const float* ca_q_b = (const float*)d_in[19];
    const float* ca_k_w = (const float*)d_in[20];
    const float* ca_k_b = (const float*)d_in[21];
    const float* ca_v_w = (const float*)d_in[22];
    const float* ca_v_b = (const float*)d_in[23];
    const float* ca_o_w = (const float*)d_in[24];
    const float* ca_o_b = (const float*)d_in[25];
    const float* ca_nq  = (const float*)d_in[26];
    const float* ca_nk  = (const float*)d_in[27];
    const float* ffn_w1 = (const float*)d_in[28];
    const float* ffn_b1 = (const float*)d_in[29];
    const float* ffn_w2 = (const float*)d_in[30];
    const float* ffn_b2 = (const float*)d_in[31];

    // ---- workspace layout (~173 MB) ----
    const size_t LC = (size_t)L_SEQ * C_DIM;            // 3,686,400
    const size_t WMAX = (size_t)C_DIM * FF_DIM;         // 13,762,560
    char* p = (char*)d_ws;
    float* ev   = (float*)p;            p += 6 * C_DIM * sizeof(float);
    float* Bcat = (float*)p;            p += 3 * C_DIM * sizeof(float);
    float* Xcur = (float*)p;            p += LC * sizeof(float);
    float* Ebuf = (float*)p;            p += LC * sizeof(float);
    float* QKV  = (float*)p;            p += 3 * LC * sizeof(float);  // fused qkv out
    unsigned short* Ab = (unsigned short*)p;  p += LC * sizeof(short);
    unsigned short* Xb = (unsigned short*)p;  p += LC * sizeof(short);
    unsigned short* Qb = (unsigned short*)p;  p += LC * sizeof(short);
    unsigned short* Kb = (unsigned short*)p;  p += LC * sizeof(short);
    unsigned short* Vt = (unsigned short*)p;  p += LC * sizeof(short);
    unsigned short* Ob = (unsigned short*)p;  p += LC * sizeof(short);
    unsigned short* W0 = (unsigned short*)p;  p += WMAX * sizeof(short);
    unsigned short* W1 = (unsigned short*)p;  p += WMAX * sizeof(short);
    unsigned short* Fb = (unsigned short*)QKV;   // [2400][8960] bf16 = 43.0 MB < 44.2 MB
    float* Pq    = QKV;                          // ca_q out [2400][1536] fp32
    float* ctxKV = QKV + LC;                     // [512][3072] fp32

    const int nLC = (int)LC;
    const float SCALE = 0.08838834764831845f;   // 1/sqrt(128)
    dim3 blk(256);
    dim3 blk512(512);
    dim3 g_qkv_256(4608 / 256, 10, 1);                  // 18 x 10 = 180 blocks
    dim3 g_proj_256(C_DIM / 256, 10, 4);                // 6 x 10 x 4 = 240 blocks, Kc=384
    dim3 g_ctxkv_256(3072 / 256, L_CTX / 256, 4);       // 12 x 2 x 4 = 96 blocks, Kc=384
    dim3 g_ff1_256(FF_DIM / 256, 10, 1);                // 35 x 10 = 350 blocks
    dim3 g_ff2_256(C_DIM / 256, 10, 4);                 // 6 x 10 x 4 = 240 blocks, Kc=2240
    dim3 g_attn((L_SEQ + 63) / 64, N_HEADS);            // 38 x 12
    dim3 g_vt_s(L_SEQ / 32, N_HEADS, 4);
    dim3 g_vt_c(L_CTX / 32, N_HEADS, 4);
    dim3 g_wt_cc(C_DIM / 32, C_DIM / 32);
    dim3 g_wt_w1(C_DIM / 32, FF_DIM / 32);
    dim3 g_wt_w2(FF_DIM / 32, C_DIM / 32);
    dim3 g_half(nLC / 512);
    dim3 g_init_cc(nLC / 1024);                         // 4 elems/thread
    dim3 g_init_kv(L_CTX * 3072 / 1024);

    k_embed<<<dim3((6 * C_DIM + 255) / 256), blk, 0, stream>>>(modulation, e, ev, 6 * C_DIM);

    // ---- phase 1: self-attention ----
    k_catbias<<<dim3((3 * C_DIM + 255) / 256), blk, 0, stream>>>(Bcat, sa_q_b, sa_k_b, sa_v_b,
                                                                 C_DIM, 3 * C_DIM);
    k_wt<<<g_wt_cc, blk, 0, stream>>>(sa_q_w, W0, C_DIM, C_DIM);
    k_wt<<<g_wt_cc, blk, 0, stream>>>(sa_k_w, W0 + (size_t)C_DIM * C_DIM, C_DIM, C_DIM);
    k_wt<<<g_wt_cc, blk, 0, stream>>>(sa_v_w, W0 + (size_t)2 * C_DIM * C_DIM, C_DIM, C_DIM);
    k_lnmod_bf16<<<dim3(L_SEQ), blk, 0, stream>>>(x, ev, 0, 1, Ab);
    k_gemm256<<<g_qkv_256, blk512, 0, stream>>>(Ab, W0, Bcat, QKV, nullptr,
                                                L_SEQ, 4608, C_DIM, C_DIM, 0, 0);
    k_wt<<<g_wt_cc, blk, 0, stream>>>(sa_o_w, W1, C_DIM, C_DIM);
    k_rms_rope_bf16<<<dim3(L_SEQ), blk, 0, stream>>>(QKV, sa_nq, freqs, 1, SCALE, Qb, 4608);
    k_rms_rope_bf16<<<dim3(L_SEQ), blk, 0, stream>>>(QKV + C_DIM, sa_nk, freqs, 1, 1.0f, Kb, 4608);
    k_vt<<<g_vt_s, blk, 0, stream>>>(QKV + 2 * C_DIM, Vt, L_SEQ, 4608);
    k_attn_mfma<<<g_attn, blk, 0, stream>>>(Qb, Kb, Vt, Ob, L_SEQ, L_SEQ);
    k_initbias<<<g_init_cc, blk, 0, stream>>>(Ebuf, sa_o_b, nLC, C_DIM);
    k_gemm256<<<g_proj_256, blk512, 0, stream>>>(Ob, W1, nullptr, Ebuf, nullptr,
                                                 L_SEQ, C_DIM, C_DIM, 384, 0, 1);
    k_resid2<<<g_half, blk, 0, stream>>>(x, Ebuf, ev, 2, Xcur, Xb, nLC);

    // ---- phase 2: cross-attention ----
    k_wt<<<g_wt_cc, blk, 0, stream>>>(ca_q_w, W0, C_DIM, C_DIM);
    k_wt<<<g_wt_cc, blk, 0, stream>>>(ca_k_w, W1, C_DIM, C_DIM);
    k_wt<<<g_wt_cc, blk, 0, stream>>>(ca_v_w, W1 + (size_t)C_DIM * C_DIM, C_DIM, C_DIM);
    k_tobf<<<dim3(L_CTX * C_DIM / 512), blk, 0, stream>>>(context, Ab, L_CTX * C_DIM);
    k_catbias<<<dim3((2 * C_DIM + 255) / 256), blk, 0, stream>>>(Bcat, ca_k_b, ca_v_b, nullptr,
                                                                 C_DIM, 2 * C_DIM);
    k_initbias<<<g_init_cc, blk, 0, stream>>>(Pq, ca_q_b, nLC, C_DIM);
    k_gemm256<<<g_proj_256, blk512, 0, stream>>>(Xb, W0, nullptr, Pq, nullptr,
                                                 L_SEQ, C_DIM, C_DIM, 384, 0, 1);
    k_initbias<<<g_init_kv, blk, 0, stream>>>(ctxKV, Bcat, L_CTX * 3072, 3072);
    k_gemm256<<<g_ctxkv_256, blk512, 0, stream>>>(Ab, W1, nullptr, ctxKV, nullptr,
                                                  L_CTX, 3072, C_DIM, 384, 0, 1);
    k_rms_rope_bf16<<<dim3(L_SEQ), blk, 0, stream>>>(Pq, ca_nq, freqs, 0, SCALE, Qb, C_DIM);
    k_rms_rope_bf16<<<dim3(L_CTX), blk, 0, stream>>>(ctxKV, ca_nk, freqs, 0, 1.0f, Kb, 3072);
    k_vt<<<g_vt_c, blk, 0, stream>>>(ctxKV + C_DIM, Vt, L_CTX, 3072);
    k_attn_mfma<<<g_attn, blk, 0, stream>>>(Qb, Kb, Vt, Ob, L_SEQ, L_CTX);
    k_wt<<<g_wt_cc, blk, 0, stream>>>(ca_o_w, W0, C_DIM, C_DIM);
    k_initbias<<<g_init_cc, blk, 0, stream>>>(Ebuf, ca_o_b, nLC, C_DIM);
    k_gemm256<<<g_proj_256, blk512, 0, stream>>>(Ob, W0, nullptr, Ebuf, nullptr,
                                                 L_SEQ, C_DIM, C_DIM, 384, 0, 1);
    k_resid2<<<g_half, blk, 0, stream>>>(Xcur, Ebuf, (const float*)nullptr, -1, Xcur, nullptr, nLC);

    // ---- phase 3: FFN (256^2 8-phase GEMMs) ----
    k_wt<<<g_wt_w1, blk, 0, stream>>>(ffn_w1, W1, C_DIM, FF_DIM);
    k_lnmod_bf16<<<dim3(L_SEQ), blk, 0, stream>>>(Xcur, ev, 3, 4, Ab);
    k_gemm256<<<g_ff1_256, blk512, 0, stream>>>(Ab, W1, ffn_b1, nullptr, Fb,
                                                L_SEQ, FF_DIM, C_DIM, C_DIM, 1, 0);
    k_wt<<<g_wt_w2, blk, 0, stream>>>(ffn_w2, W0, FF_DIM, C_DIM);
    k_initbias<<<g_init_cc, blk, 0, stream>>>(Ebuf, ffn_b2, nLC, C_DIM);
    k_gemm256<<<g_ff2_256, blk512, 0, stream>>>(Fb, W0, nullptr, Ebuf, nullptr,
                                                L_SEQ, C_DIM, FF_DIM, 2240, 0, 1);
    k_resid2<<<g_half, blk, 0, stream>>>(Xcur, Ebuf, ev, 5, (float*)d_out, nullptr, nLC);
}